// Round 11
// baseline (813.171 us; speedup 1.0000x reference)
//
#include <hip/hip_runtime.h>
#include <hip/hip_bf16.h>
#include <cstddef>

typedef __hip_bfloat16 bf;
typedef __attribute__((ext_vector_type(8))) short short8x;
typedef __attribute__((ext_vector_type(4))) float f32x4;

__device__ __forceinline__ float ldv(const float* p){ return *p; }
__device__ __forceinline__ float ldv(const bf* p){ return __bfloat162float(*p); }
__device__ __forceinline__ void stv(float* p, float v){ *p = v; }
__device__ __forceinline__ void stv(bf* p, float v){ *p = __float2bfloat16(v); }
__device__ __forceinline__ float sigm(float x){ return 1.f/(1.f + __expf(-x)); }
__device__ __forceinline__ short bfbits(float v){
  __hip_bfloat16 h = __float2bfloat16(v);
  return *(short*)&h;
}

__device__ __forceinline__ float ldin(const void* p, long i, int f32){
  return f32 ? ((const float*)p)[i] : __bfloat162float(((const bf*)p)[i]);
}

// XOR-swizzle on 16B-unit index (involution; applied at write AND read).
__device__ __forceinline__ int swz(int u){ return u ^ ((u >> 3) & 7); }

template<int K>
__device__ __forceinline__ int rot_src(int r, int t){
  int u = t / K, v = t % K;
  int s1 = v*K + (K-1-u);
  int s2 = (K-1-u)*K + (K-1-v);
  int s3 = (K-1-v)*K + u;
  return r==0 ? t : (r==1 ? s1 : (r==2 ? s2 : s3));
}

// 12-tap MFMA for two m-tiles; A from swizzled LDS layout xin5[swz(g*HW+sp)][8] (g=ch/8),
// B held in registers (loaded once per nt from global btg).
// Tap/accumulation order identical to verified rounds: main 0..8 then tail 0..2, acc0 then acc1.
template<int HW_, int WIN>
__device__ __forceinline__ void conv12x2(const short* __restrict__ xin5, int b0, int b1, int lq,
                                         const short8x (&bm)[9], const short8x (&bt)[3],
                                         const int (&tdh)[3], const int (&tdw)[3],
                                         f32x4& acc0, f32x4& acc1){
  short8x A[9];
  #pragma unroll
  for (int t = 0; t < 9; ++t)
    A[t] = *(const short8x*)&xin5[swz(lq*HW_ + b0 + (t/3)*WIN + (t%3))*8];
  #pragma unroll
  for (int t = 0; t < 9; ++t)
    acc0 = __builtin_amdgcn_mfma_f32_16x16x32_bf16(A[t], bm[t], acc0, 0, 0, 0);
  #pragma unroll
  for (int tg = 0; tg < 3; ++tg){
    short8x a = *(const short8x*)&xin5[swz(4*HW_ + b0 + tdh[tg]*WIN + tdw[tg])*8];
    acc0 = __builtin_amdgcn_mfma_f32_16x16x32_bf16(a, bt[tg], acc0, 0, 0, 0);
  }
  #pragma unroll
  for (int t = 0; t < 9; ++t){
    short8x a = *(const short8x*)&xin5[swz(lq*HW_ + b1 + (t/3)*WIN + (t%3))*8];
    acc1 = __builtin_amdgcn_mfma_f32_16x16x32_bf16(a, bm[t], acc1, 0, 0, 0);
  }
  #pragma unroll
  for (int tg = 0; tg < 3; ++tg){
    short8x a = *(const short8x*)&xin5[swz(4*HW_ + b1 + tdh[tg]*WIN + tdw[tg])*8];
    acc1 = __builtin_amdgcn_mfma_f32_16x16x32_bf16(a, bt[tg], acc1, 0, 0, 0);
  }
}

// ---------------- dtype detection ----------------
__global__ void k_detect(const void* x, int* ctrl){
  int lane = threadIdx.x;
  float mx = 0.f;
  for (int i = lane; i < 2048; i += 64){
    float v = __bfloat162float(((const bf*)x)[i]);
    if (v != v) v = 1e30f;
    mx = fmaxf(mx, fabsf(v));
  }
  #pragma unroll
  for (int off = 32; off > 0; off >>= 1) mx = fmaxf(mx, __shfl_xor(mx, off));
  if (lane == 0) ctrl[0] = (mx > 1e6f) ? 1 : 0;
}

// ---------------- build MFMA B-frag buffers (tail-merged layout), 18432 shorts/layer ----------------
__global__ __launch_bounds__(256) void k_build_bt(const void* c2, const void* c3, const void* c4,
                                                  const int* __restrict__ ctrl, short* __restrict__ btg){
  const void* ws[3] = {c2, c3, c4};
  const void* cw = ws[blockIdx.x];
  short* outp = btg + blockIdx.x * 18432;
  int f32 = ctrl[0];
  for (int i = threadIdx.x; i < 18432; i += 256){
    int t, n, k;
    bool valid;
    if (i < 13824){
      t = i / 1536;
      int rem = i % 1536;
      int kq = rem / 384;
      n = (i >> 3) % 48;
      k = kq*8 + (i & 7);
      valid = (n < 40);
    } else {
      int j2 = i - 13824;
      int tg = j2 / 1536;
      int lq = (j2 % 1536) / 384;
      n = (j2 >> 3) % 48;
      k = 32 + (i & 7);
      t = tg*4 + lq;
      valid = (t < 9) && (n < 40);
    }
    float v = 0.f;
    if (valid){
      int o = n >> 2, r = n & 3, ci = k >> 2, s = k & 3;
      v = ldin(cw, ((o*10 + ci)*4 + ((s - r) & 3))*9 + rot_src<3>(r, t), f32);
    }
    outp[i] = bfbits(v);
  }
}

// ---------------- L1 fused (2 batch items/block): att1 gate + xa write + conv1 bn1-stats ----------------
__global__ __launch_bounds__(1024) void k_l1(const void* __restrict__ x,
                                             const void* __restrict__ a1,
                                             const void* __restrict__ c1,
                                             const int* __restrict__ ctrl,
                                             float* __restrict__ xa,
                                             float* __restrict__ ssum, float* __restrict__ ssq){
  __shared__ float xs[2][784];
  __shared__ float ws[49];
  __shared__ float xg[2][28*29];
  __shared__ float wr1[360];
  __shared__ float lsum[16], lss[16];
  int b0 = blockIdx.x*2, tid = threadIdx.x;
  int f32 = ctrl[0];
  for (int i = tid; i < 1568; i += 1024){
    int bi = i / 784, p = i % 784;
    xs[bi][p] = ldin(x, (long)(b0 + bi)*784 + p, f32);
  }
  if (tid < 49) ws[tid] = ldin(a1, tid, f32) + ldin(a1, 49 + tid, f32);
  for (int i = tid; i < 360; i += 1024){
    int r = i / 90, rem = i % 90, o = rem / 9, t = rem % 9;
    wr1[i] = ldin(c1, o*9 + rot_src<3>(r, t), f32);
  }
  if (tid < 16){ lsum[tid] = 0.f; lss[tid] = 0.f; }
  __syncthreads();
  for (int p2 = tid; p2 < 1568; p2 += 1024){
    int bi = p2 / 784, p = p2 % 784;
    int h = p / 28, w = p % 28;
    float acc = 0.f;
    #pragma unroll
    for (int u = 0; u < 7; ++u){
      int hh = h + u - 3;
      if (hh < 0 || hh >= 28) continue;
      #pragma unroll
      for (int v = 0; v < 7; ++v){
        int ww = w + v - 3;
        if (ww < 0 || ww >= 28) continue;
        acc = fmaf(xs[bi][hh*28 + ww], ws[u*7 + v], acc);
      }
    }
    float g = xs[bi][p] * sigm(acc);
    xg[bi][h*29 + w] = g;
    xa[(size_t)(b0 + bi)*784 + p] = g;
  }
  __syncthreads();
  for (int it = tid; it < 2080; it += 1024){
    int bi = it / 1040, j = it % 1040;
    int o = j / 104, rem = j % 104, r = rem / 26, h = rem % 26;
    float wt[9];
    #pragma unroll
    for (int t = 0; t < 9; ++t) wt[t] = wr1[(r*10 + o)*9 + t];
    float acc[26];
    #pragma unroll
    for (int w = 0; w < 26; ++w) acc[w] = 0.f;
    #pragma unroll
    for (int u = 0; u < 3; ++u){
      float rr[28];
      #pragma unroll
      for (int j2 = 0; j2 < 28; ++j2) rr[j2] = xg[bi][(h + u)*29 + j2];
      #pragma unroll
      for (int v = 0; v < 3; ++v){
        float wv = wt[u*3 + v];
        #pragma unroll
        for (int w = 0; w < 26; ++w) acc[w] = fmaf(rr[w + v], wv, acc[w]);
      }
    }
    float s1 = 0.f, s2 = 0.f;
    #pragma unroll
    for (int w = 0; w < 26; ++w){ s1 += acc[w]; s2 += acc[w]*acc[w]; }
    atomicAdd(&lsum[o], s1); atomicAdd(&lss[o], s2);
  }
  __syncthreads();
  if (tid < 10){ atomicAdd(&ssum[tid], lsum[tid]); atomicAdd(&ssq[tid], lss[tid]); }
}

// ---------------- L2 attention (2 batch items/block; finalize prologue; 13-wide half-rows) ----------------
__global__ __launch_bounds__(512) void k_att2(const float* __restrict__ xa,
                                              const void* __restrict__ c1,
                                              const float* __restrict__ psum,
                                              const float* __restrict__ psq,
                                              const void* __restrict__ g,
                                              const void* __restrict__ bb,
                                              float invN,
                                              const void* __restrict__ aw,
                                              const int* __restrict__ ctrl,
                                              float* __restrict__ attf){
  __shared__ float xs[2][28*29];
  __shared__ float wr1[360];
  __shared__ float ps[2][8*26*33];
  __shared__ float wl[1568];
  __shared__ float scs[10], shs[10];
  int b0 = blockIdx.x*2, tid = threadIdx.x;
  int f32 = ctrl[0];
  if (tid < 10){
    float m = psum[tid] * invN;
    float v = fmaxf(psq[tid] * invN - m*m, 0.f);
    float sc = ldin(g, tid, f32) * rsqrtf(v + 2e-5f);
    scs[tid] = sc;
    shs[tid] = ldin(bb, tid, f32) - m * sc;
  }
  for (int i = tid; i < 1568; i += 512){
    int bi = i / 784, p = i % 784;
    int row = p / 28, col = p % 28;
    xs[bi][row*29 + col] = xa[(size_t)(b0 + bi)*784 + p];
  }
  for (int i = tid; i < 360; i += 512){
    int r = i / 90, rem = i % 90, o = rem / 9, t = rem % 9;
    wr1[i] = ldin(c1, o*9 + rot_src<3>(r, t), f32);
  }
  for (int i = tid; i < 2*8*26*33; i += 512) ps[i / 6864][i % 6864] = 0.f;
  for (int i = tid; i < 1568; i += 512){
    int r = i / 392, rem = i % 392, i2 = rem / 196, s = (rem % 196)/49, t = rem % 49;
    int sp = (s - r) & 3;
    wl[i] = ldin(aw, (i2*4 + sp)*49 + rot_src<7>(r, t), f32);
  }
  __syncthreads();
  if (tid < 416){
    int bi = tid / 208, j = tid % 208;
    int pair = j >> 1, half = j & 1;
    int s = pair / 26, h = pair % 26;
    int w0 = half*13;
    float msum[13], mmax[13];
    #pragma unroll
    for (int w = 0; w < 13; ++w){ msum[w] = 0.f; mmax[w] = 0.f; }
    for (int o = 0; o < 10; ++o){
      const float* wb = wr1 + (s*10 + o)*9;
      float acc[13];
      #pragma unroll
      for (int w = 0; w < 13; ++w) acc[w] = 0.f;
      #pragma unroll
      for (int u = 0; u < 3; ++u){
        float rr[15];
        #pragma unroll
        for (int j2 = 0; j2 < 15; ++j2) rr[j2] = xs[bi][(h + u)*29 + w0 + j2];
        #pragma unroll
        for (int v = 0; v < 3; ++v){
          float wv = wb[u*3 + v];
          #pragma unroll
          for (int w = 0; w < 13; ++w) acc[w] = fmaf(rr[w + v], wv, acc[w]);
        }
      }
      float a_sc = scs[o], a_sh = shs[o];
      #pragma unroll
      for (int w = 0; w < 13; ++w){
        float val = fmaxf(fmaf(acc[w], a_sc, a_sh), 0.f);
        msum[w] += val; mmax[w] = fmaxf(mmax[w], val);
      }
    }
    #pragma unroll
    for (int w = 0; w < 13; ++w){
      ps[bi][s*858 + h*33 + 3 + w0 + w] = msum[w] * 0.1f;
      ps[bi][(4 + s)*858 + h*33 + 3 + w0 + w] = mmax[w];
    }
  }
  __syncthreads();
  if (tid < 416){
    int bi = tid / 208, j = tid % 208;
    int pair = j >> 1, half = j & 1;
    int r = pair / 26, h = pair % 26;
    int w0 = half*13;
    float acc[13];
    #pragma unroll
    for (int w = 0; w < 13; ++w) acc[w] = 0.f;
    for (int c = 0; c < 8; ++c){
      const float* wb = wl + r*392 + c*49;
      const float* pb = ps[bi] + c*858;
      #pragma unroll
      for (int u = 0; u < 7; ++u){
        int row = h + u - 3;
        if (row < 0 || row >= 26) continue;
        float rr[19];
        #pragma unroll
        for (int j2 = 0; j2 < 19; ++j2) rr[j2] = pb[row*33 + w0 + j2];
        #pragma unroll
        for (int v = 0; v < 7; ++v){
          float wv = wb[u*7 + v];
          #pragma unroll
          for (int w = 0; w < 13; ++w) acc[w] = fmaf(rr[w + v], wv, acc[w]);
        }
      }
    }
    size_t base = ((size_t)(b0 + bi)*4 + r)*676 + (size_t)h*26 + w0;
    #pragma unroll
    for (int w = 0; w < 13; ++w) attf[base + w] = sigm(acc[w]);
  }
}

// ---------------- L2 conv via MFMA: 512 thr (R5/R7-proven), nt-outer B-in-regs + swizzled xin5 ----------------
__global__ __launch_bounds__(512, 4) void k_conv2m(const float* __restrict__ xa,
                                                const void* __restrict__ c1,
                                                const float* __restrict__ psum,
                                                const float* __restrict__ psq,
                                                const void* __restrict__ g,
                                                const void* __restrict__ bb,
                                                float invN,
                                                const float* __restrict__ attm,
                                                const short* __restrict__ btg,
                                                const int* __restrict__ ctrl,
                                                bf* __restrict__ ap2,
                                                float* __restrict__ ssum, float* __restrict__ ssq){
  __shared__ alignas(16) float xs2[784];
  __shared__ float wr1[360];
  __shared__ alignas(16) float attL[4*676];
  __shared__ alignas(16) short xin5[3384*8];   // units padded to %8 for swizzle
  __shared__ float lsum[16], lss[16];
  __shared__ float scs[10], shs[10];
  int tid = threadIdx.x, b = blockIdx.x;
  int f32 = ctrl[0];
  if (tid < 10){
    float m = psum[tid] * invN;
    float v = fmaxf(psq[tid] * invN - m*m, 0.f);
    float sc = ldin(g, tid, f32) * rsqrtf(v + 2e-5f);
    scs[tid] = sc;
    shs[tid] = ldin(bb, tid, f32) - m * sc;
  }
  for (int i = tid; i < 784; i += 512) xs2[i] = xa[(size_t)b*784 + i];
  for (int i = tid; i < 360; i += 512){
    int r = i / 90, rem = i % 90, o = rem / 9, t = rem % 9;
    wr1[i] = ldin(c1, o*9 + rot_src<3>(r, t), f32);
  }
  for (int i = tid; i < 2704; i += 512) attL[i] = attm[(size_t)b*2704 + i];
  if (tid < 16){ lsum[tid] = 0.f; lss[tid] = 0.f; }
  __syncthreads();
  for (int it = tid; it < 1040; it += 512){
    int row = it / 40, ch = it % 40;
    int ci = ch >> 2, s = ch & 3;
    float wt[9];
    {
      const float* wb = wr1 + (s*10 + ci)*9;
      #pragma unroll
      for (int t = 0; t < 9; ++t) wt[t] = wb[t];
    }
    float sc = scs[ci], sh = shs[ci];
    float acc[26];
    #pragma unroll
    for (int w = 0; w < 26; ++w) acc[w] = 0.f;
    #pragma unroll
    for (int u = 0; u < 3; ++u){
      float rr[28];
      const float4* rp = (const float4*)(xs2 + (row + u)*28);
      #pragma unroll
      for (int j = 0; j < 7; ++j){ float4 q = rp[j]; rr[4*j]=q.x; rr[4*j+1]=q.y; rr[4*j+2]=q.z; rr[4*j+3]=q.w; }
      #pragma unroll
      for (int v = 0; v < 3; ++v){
        float wv = wt[u*3 + v];
        #pragma unroll
        for (int w = 0; w < 26; ++w) acc[w] = fmaf(rr[w + v], wv, acc[w]);
      }
    }
    const float* ap = attL + s*676 + row*26;
    int gbase = (ch >> 3)*676 + row*26;
    int c7 = ch & 7;
    #pragma unroll
    for (int w = 0; w < 26; ++w){
      float v = fmaxf(fmaf(acc[w], sc, sh), 0.f) * ap[w];
      xin5[swz(gbase + w)*8 + c7] = bfbits(v);
    }
  }
  __syncthreads();

  int wv = tid >> 6, lane = tid & 63, lm = lane & 15, lq = lane >> 4;
  short8x bmain[9], btail[3];
  int tdh[3], tdw[3];
  #pragma unroll
  for (int tg = 0; tg < 3; ++tg){
    int tap = tg*4 + lq; if (tap > 8) tap = 8;
    tdh[tg] = tap / 3; tdw[tg] = tap % 3;
  }
  int curNt = -1, n = 0, o = 0;
  for (int u = wv; u < 54; u += 8){
    int nt = u / 18, mp = u % 18;
    if (nt != curNt){
      curNt = nt; n = nt*16 + lm; o = n >> 2;
      #pragma unroll
      for (int t = 0; t < 9; ++t)
        bmain[t] = *(const short8x*)(btg + (((t*4 + lq)*48 + n) << 3));
      #pragma unroll
      for (int tg = 0; tg < 3; ++tg)
        btail[tg] = *(const short8x*)(btg + 13824 + (((tg*4 + lq)*48 + n) << 3));
    }
    int mt0 = mp*2, mt1 = mp*2 + 1;
    int mA0 = mt0*16 + lm, mA1 = mt1*16 + lm;
    int qi0 = mA0 >> 2, sub0 = mA0 & 3;
    int h00 = 2*(qi0/12) + (sub0 >> 1), w00 = 2*(qi0%12) + (sub0 & 1);
    int qi1 = mA1 >> 2, sub1 = mA1 & 3;
    int h01 = 2*(qi1/12) + (sub1 >> 1), w01 = 2*(qi1%12) + (sub1 & 1);
    f32x4 acc0 = {0.f,0.f,0.f,0.f}, acc1 = {0.f,0.f,0.f,0.f};
    conv12x2<676,26>(xin5, h00*26 + w00, h01*26 + w01, lq, bmain, btail, tdh, tdw, acc0, acc1);
    if (n < 40){
      float s1 = acc0[0]+acc0[1]+acc0[2]+acc0[3] + acc1[0]+acc1[1]+acc1[2]+acc1[3];
      float s2 = acc0[0]*acc0[0]+acc0[1]*acc0[1]+acc0[2]*acc0[2]+acc0[3]*acc0[3]
               + acc1[0]*acc1[0]+acc1[1]*acc1[1]+acc1[2]*acc1[2]+acc1[3]*acc1[3];
      atomicAdd(&lsum[o], s1); atomicAdd(&lss[o], s2);
      float mx0 = fmaxf(fmaxf(acc0[0], acc0[1]), fmaxf(acc0[2], acc0[3]));
      float mx1 = fmaxf(fmaxf(acc1[0], acc1[1]), fmaxf(acc1[2], acc1[3]));
      size_t pbase = ((size_t)b*40 + n)*144;
      stv(ap2 + pbase + mt0*4 + lq, mx0);
      stv(ap2 + pbase + mt1*4 + lq, mx1);
    }
  }
  __syncthreads();
  if (tid < 10){ atomicAdd(&ssum[tid], lsum[tid]); atomicAdd(&ssq[tid], lss[tid]); }
}

// ---------------- generic GG conv via MFMA (L3/L4): coalesced staging + nt-outer B-in-regs ----------------
template<int HIN, int NT, typename TI>
__global__ __launch_bounds__(NT) void k_conv_ggm(const TI* __restrict__ act,
                                                 const float* __restrict__ psum,
                                                 const float* __restrict__ psq,
                                                 const void* __restrict__ g,
                                                 const void* __restrict__ bb,
                                                 float invN,
                                                 const float* __restrict__ attm,
                                                 const short* __restrict__ btg,
                                                 const int* __restrict__ ctrl,
                                                 float* __restrict__ out,
                                                 float* __restrict__ ssum, float* __restrict__ ssq){
  constexpr int WIN = HIN, HOUT = HIN - 2, WOUT = WIN - 2;
  constexpr int M = HOUT*WOUT, HW = HIN*WIN;
  constexpr int MT = (M + 15)/16, MU = (MT + 1)/2, UNITS = MU*3;
  constexpr int NWV = NT/64;
  constexpr int UP = ((5*HW + 7)/8)*8;
  __shared__ alignas(16) short xin5[UP*8];
  __shared__ float lsum[16], lss[16];
  __shared__ float scs[10], shs[10];
  int tid = threadIdx.x, b = blockIdx.x;
  int f32 = ctrl[0];
  if (tid < 10){
    float m = psum[tid]*invN;
    float v = fmaxf(psq[tid]*invN - m*m, 0.f);
    float sc = ldin(g, tid, f32)*rsqrtf(v + 2e-5f);
    scs[tid] = sc; shs[tid] = ldin(bb, tid, f32) - m*sc;
  }
  if (tid < 16){ lsum[tid] = 0.f; lss[tid] = 0.f; }
  __syncthreads();
  // coalesced: consecutive lanes -> consecutive sp within one channel
  for (int i = tid; i < HW*40; i += NT){
    int ch = i / HW, sp = i % HW;
    int ci = ch >> 2, s = ch & 3;
    float a = ldv(act + ((size_t)b*40 + ch)*HW + sp);
    a = fmaxf(fmaf(a, scs[ci], shs[ci]), 0.f);
    float v = a * attm[((size_t)b*4 + s)*HW + sp];
    xin5[swz((ch >> 3)*HW + sp)*8 + (ch & 7)] = bfbits(v);
  }
  __syncthreads();
  int wv = tid >> 6, lane = tid & 63, lm = lane & 15, lq = lane >> 4;
  short8x bmain[9], btail[3];
  int tdh[3], tdw[3];
  #pragma unroll
  for (int tg = 0; tg < 3; ++tg){
    int tap = tg*4 + lq; if (tap > 8) tap = 8;
    tdh[tg] = tap / 3; tdw[tg] = tap % 3;
  }
  int curNt = -1, n = 0, o = 0;
  for (int u = wv; u < UNITS; u += NWV){
    int nt = u / MU, mu = u % MU;
    if (nt != curNt){
      curNt = nt; n = nt*16 + lm; o = n >> 2;
      #pragma unroll
      for (int t = 0; t < 9; ++t)
        bmain[t] = *(const short8x*)(btg + (((t*4 + lq)*48 + n) << 3));
      #pragma unroll
      for (int tg = 0; tg < 3; ++tg)
        btail[tg] = *(const short8x*)(btg + 13824 + (((tg*4 + lq)*48 + n) << 3));
    }
    int mt0 = mu*2, mt1 = mu*2 + 1;
    int mA0 = mt0*16 + lm; if (mA0 > M-1) mA0 = M-1;
    int mA1 = mt1*16 + lm; if (mA1 > M-1) mA1 = M-1;
    int base0 = (mA0 / WOUT)*WIN + (mA0 % WOUT);
    int base1 = (mA1 / WOUT)*WIN + (mA1 % WOUT);
    f32x4 acc0 = {0.f,0.f,0.f,0.f}, acc1 = {0.f,0.f,0.f,0.f};
    conv12x2<HW,WIN>(xin5, base0, base1, lq, bmain, btail, tdh, tdw, acc0, acc1);
    if (n < 40){
      float s1 = 0.f, s2 = 0.f;
      size_t obase = ((size_t)b*40 + n)*M;
      #pragma unroll
      for (int reg = 0; reg < 4; ++reg){
        int m0 = mt0*16 + lq*4 + reg;
        if (m0 < M){ float v = acc0[reg]; s1 += v; s2 += v*v; out[obase + m0] = v; }
        int m1 = mt1*16 + lq*4 + reg;
        if (m1 < M){ float v = acc1[reg]; s1 += v; s2 += v*v; out[obase + m1] = v; }
      }
      atomicAdd(&lsum[o], s1); atomicAdd(&lss[o], s2);
    }
  }
  __syncthreads();
  if (tid < 10){ atomicAdd(&ssum[tid], lsum[tid]); atomicAdd(&ssq[tid], lss[tid]); }
}

// ---------------- generic GG spatial attention (L3..L7): BI batch items per block ----------------
template<int H, int W, int NT, int BI, typename TA>
__global__ __launch_bounds__(NT) void k_att_gg(const TA* __restrict__ act,
                                               const float* __restrict__ psum,
                                               const float* __restrict__ psq,
                                               const void* __restrict__ g,
                                               const void* __restrict__ bb,
                                               float invN,
                                               const void* __restrict__ aw,
                                               const int* __restrict__ ctrl,
                                               float* __restrict__ att){
  constexpr int WG = (W + 6) | 1;
  constexpr int HW = H*W;
  constexpr int WH = W/2;
  constexpr int PSN = 8*H*WG;
  __shared__ float ps[BI][PSN];
  __shared__ float wl[1568];
  __shared__ float scs[10], shs[10];
  int b0 = blockIdx.x*BI, tid = threadIdx.x;
  int f32 = ctrl[0];
  if (tid < 10){
    float m = psum[tid]*invN;
    float v = fmaxf(psq[tid]*invN - m*m, 0.f);
    float sc = ldin(g, tid, f32)*rsqrtf(v + 2e-5f);
    scs[tid] = sc; shs[tid] = ldin(bb, tid, f32) - m*sc;
  }
  for (int i = tid; i < 1568; i += NT){
    int r = i / 392, rem = i % 392, i2 = rem / 196, s = (rem % 196)/49, t = rem % 49;
    int sp = (s - r) & 3;
    wl[i] = ldin(aw, (i2*4 + sp)*49 + rot_src<7>(r, t), f32);
  }
  __syncthreads();
  for (int i = tid; i < BI*4*H*WG; i += NT){
    int bi = i / (4*H*WG), rem0 = i % (4*H*WG);
    int b = b0 + bi;
    int s = rem0 / (H*WG), rem = rem0 % (H*WG), row = rem / WG, col = rem % WG;
    int cc = col - 3;
    float mn = 0.f, mx = 0.f;
    if (cc >= 0 && cc < W){
      float sum = 0.f; mx = 0.f;
      const TA* ap = act + (size_t)b*40*HW + (size_t)s*HW + row*W + cc;
      #pragma unroll
      for (int c = 0; c < 10; ++c){
        float v = fmaxf(fmaf(ldv(ap + (size_t)c*4*HW), scs[c], shs[c]), 0.f);
        sum += v; mx = fmaxf(mx, v);
      }
      mn = sum * 0.1f;
    }
    ps[bi][s*H*WG + row*WG + col] = mn;
    ps[bi][(4 + s)*H*WG + row*WG + col] = mx;
  }
  __syncthreads();
  for (int it = tid; it < BI*8*H; it += NT){
    int bi = it / (8*H), rem0 = it % (8*H);
    int b = b0 + bi;
    int r = rem0 / (2*H), rem2 = rem0 % (2*H), h = rem2 >> 1, half = rem2 & 1;
    int w0 = half*WH;
    float acc[WH];
    #pragma unroll
    for (int w = 0; w < WH; ++w) acc[w] = 0.f;
    for (int c = 0; c < 8; ++c){
      const float* wb = wl + r*392 + c*49;
      const float* pb = ps[bi] + c*H*WG;
      #pragma unroll
      for (int u = 0; u < 7; ++u){
        int row = h + u - 3;
        if (row < 0 || row >= H) continue;
        float rr[WH + 6];
        #pragma unroll
        for (int j = 0; j < WH + 6; ++j) rr[j] = pb[row*WG + w0 + j];
        #pragma unroll
        for (int v = 0; v < 7; ++v){
          float wv = wb[u*7 + v];
          #pragma unroll
          for (int w = 0; w < WH; ++w) acc[w] = fmaf(rr[w + v], wv, acc[w]);
        }
      }
    }
    size_t base = ((size_t)b*4 + r)*HW + (size_t)h*W + w0;
    #pragma unroll
    for (int w = 0; w < WH; ++w) att[base + w] = sigm(acc[w]);
  }
}

// ---------------- fp32 GG conv (L5..L7): 2 batch items per block ----------------
template<int HIN, int K, int SR, int NT, bool STATS, bool FINAL, typename TI>
__global__ __launch_bounds__(NT) void k_conv_gg(const TI* __restrict__ act,
                                                const float* __restrict__ psum,
                                                const float* __restrict__ psq,
                                                const void* __restrict__ g,
                                                const void* __restrict__ bb,
                                                float invN,
                                                const float* __restrict__ attm,
                                                const void* __restrict__ cw,
                                                const int* __restrict__ ctrl,
                                                void* __restrict__ out,
                                                float* __restrict__ ssum, float* __restrict__ ssq){
  constexpr int WIN  = HIN;
  constexpr int HOUT = HIN - K + 1;
  constexpr int WOUT = WIN - K + 1;
  constexpr int NS   = HOUT / SR;
  constexpr int WP   = WIN | 1;
  constexpr int NW   = 10*10*4*K*K;
  constexpr int HW   = HIN*WIN;
  constexpr int XN   = 40*HIN*WP;
  __shared__ float xin[2][XN];
  __shared__ float wl[NW];
  __shared__ float lsum[16], lss[16];
  __shared__ float scs[10], shs[10];
  __shared__ float red[2][48];
  int tid = threadIdx.x;
  int b0 = blockIdx.x*2;
  int f32 = ctrl[0];
  if (tid < 10){
    float m = psum[tid]*invN;
    float v = fmaxf(psq[tid]*invN - m*m, 0.f);
    float sc = ldin(g, tid, f32)*rsqrtf(v + 2e-5f);
    scs[tid] = sc; shs[tid] = ldin(bb, tid, f32) - m*sc;
  }
  if (STATS && tid < 16){ lsum[tid] = 0.f; lss[tid] = 0.f; }
  for (int i = tid; i < NW; i += NT) wl[i] = ldin(cw, i, f32);
  __syncthreads();
  for (int i = tid; i < 2*XN; i += NT){
    int bi = i / XN, rem0 = i % XN;
    int b = b0 + bi;
    int c = rem0 / (HIN*WP), rem = rem0 % (HIN*WP), rr = rem / WP, col = rem % WP;
    float v = 0.f;
    if (col < WIN){
      int ch = c >> 2, s = c & 3;
      float a = ldv(act + ((size_t)b*40 + c)*HW + (size_t)rr*WIN + col);
      a = fmaxf(fmaf(a, scs[ch], shs[ch]), 0.f);
      v = a * attm[((size_t)b*4 + s)*HW + (size_t)rr*WIN + col];
    }
    xin[bi][rem0] = v;
  }
  __syncthreads();
  for (int it = tid; it < 2*40*NS; it += NT){
    int bi = it / (40*NS), rem0 = it % (40*NS);
    int b = b0 + bi;
    int o = rem0 / (4*NS), rem = rem0 % (4*NS), r = rem / NS, hs = rem % NS;
    int h0 = hs * SR;
    int perm[K*K];
    #pragma unroll
    for (int t = 0; t < K*K; ++t) perm[t] = rot_src<K>(r, t);
    float acc[SR][WOUT];
    #pragma unroll
    for (int a = 0; a < SR; ++a)
      #pragma unroll
      for (int w = 0; w < WOUT; ++w) acc[a][w] = 0.f;
    for (int ci = 0; ci < 10; ++ci){
      #pragma unroll
      for (int s = 0; s < 4; ++s){
        int sp = (s - r) & 3;
        const float* wb = wl + (size_t)((o*10 + ci)*4 + sp)*K*K;
        float wt[K*K];
        #pragma unroll
        for (int t = 0; t < K*K; ++t) wt[t] = wb[perm[t]];
        const float* ib = xin[bi] + (ci*4 + s)*HIN*WP;
        #pragma unroll
        for (int ri = 0; ri < SR + K - 1; ++ri){
          float rr3[WP];
          #pragma unroll
          for (int j = 0; j < WP; ++j) rr3[j] = ib[(h0 + ri)*WP + j];
          #pragma unroll
          for (int u = 0; u < K; ++u){
            int orr = ri - u;
            if (orr < 0 || orr >= SR) continue;
            #pragma unroll
            for (int v = 0; v < K; ++v){
              float wv = wt[u*K + v];
              #pragma unroll
              for (int w = 0; w < WOUT; ++w) acc[orr][w] = fmaf(rr3[w + v], wv, acc[orr][w]);
            }
          }
        }
      }
    }
    if constexpr (STATS){
      float s1 = 0.f, s2 = 0.f;
      #pragma unroll
      for (int a = 0; a < SR; ++a)
        #pragma unroll
        for (int w = 0; w < WOUT; ++w){ s1 += acc[a][w]; s2 += acc[a][w]*acc[a][w]; }
      atomicAdd(&lsum[o], s1); atomicAdd(&lss[o], s2);
    }
    if constexpr (FINAL){
      red[bi][o*4 + r] = acc[0][0];
    } else {
      #pragma unroll
      for (int a = 0; a < SR; ++a){
        size_t base = ((size_t)b*40 + o*4 + r)*HOUT*WOUT + (size_t)(h0 + a)*WOUT;
        #pragma unroll
        for (int w = 0; w < WOUT; ++w) ((float*)out)[base + w] = acc[a][w];
      }
    }
  }
  if constexpr (STATS){
    __syncthreads();
    if (tid < 10){ atomicAdd(&ssum[tid], lsum[tid]); atomicAdd(&ssq[tid], lss[tid]); }
  }
  if constexpr (FINAL){
    __syncthreads();
    if (tid < 20){
      int bi = tid / 10, c = tid % 10;
      float m4 = fmaxf(fmaxf(red[bi][c*4], red[bi][c*4+1]), fmaxf(red[bi][c*4+2], red[bi][c*4+3]));
      if (f32) ((float*)out)[(size_t)(b0 + bi)*10 + c] = m4;
      else stv((bf*)out + (size_t)(b0 + bi)*10 + c, m4);
    }
  }
}

extern "C" void kernel_launch(void* const* d_in, const int* in_sizes, int n_in,
                              void* d_out, int out_size, void* d_ws, size_t ws_size,
                              hipStream_t stream){
  (void)in_sizes; (void)n_in; (void)out_size; (void)ws_size;
  const void* x  = d_in[0];
  const void* c1 = d_in[1];
  const void* a1 = d_in[2];
  const void* c2 = d_in[3];
  const void* a2 = d_in[4];
  const void* c3 = d_in[5];
  const void* a3 = d_in[6];
  const void* c4 = d_in[7];
  const void* a4 = d_in[8];
  const void* c5 = d_in[9];
  const void* a5 = d_in[10];
  const void* c6 = d_in[11];
  const void* a6 = d_in[12];
  const void* c7 = d_in[13];
  const void* a7 = d_in[14];
  const void* bng[6] = {d_in[15],d_in[17],d_in[19],d_in[21],d_in[23],d_in[25]};
  const void* bnb[6] = {d_in[16],d_in[18],d_in[20],d_in[22],d_in[24],d_in[26]};

  // ---- arena ----
  size_t off = 0;
  char* wsb = (char*)d_ws;
  auto alloc = [&](size_t bytes)->void*{ void* p = wsb + off; off += (bytes + 255) & ~(size_t)255; return p; };
  int*   ctrl   = (int*)alloc(256);
  float* stats  = (float*)alloc(192*sizeof(float));
  float* scales = (float*)alloc(192*sizeof(float));
  (void)scales;
  short* btfr   = (short*)alloc(3*18432*2);
  char*  region1 = (char*)alloc(28573696);
  bf*    ap2 = (bf*)alloc((size_t)2048*40*144*2);
  float* yD  = (float*)alloc((size_t)2048*40*100*4);
  float* xa    = (float*)region1;
  float* attf2 = (float*)(region1 + 6422528);
  float* yE    = (float*)region1;
  float* attf3 = (float*)(region1 + 20971520);

  hipMemsetAsync(ctrl, 0, 1024, stream);
  k_detect<<<1, 64, 0, stream>>>(x, ctrl);
  k_build_bt<<<3, 256, 0, stream>>>(c2, c3, c4, ctrl, btfr);

  // L1 (2 items/block)
  k_l1<<<1024, 1024, 0, stream>>>(x, a1, c1, ctrl, xa, stats + 0, stats + 16);

  // L2 (bn1 finalize fused in consumers; att2 2 items/block)
  k_att2<<<1024, 512, 0, stream>>>(xa, c1, stats + 0, stats + 16, bng[0], bnb[0],
                                   1.f/5537792.f, a2, ctrl, attf2);
  k_conv2m<<<2048, 512, 0, stream>>>(xa, c1, stats + 0, stats + 16, bng[0], bnb[0],
                                     1.f/5537792.f, attf2, btfr, ctrl, ap2, stats + 32, stats + 48);

  // L3: 12->10 (MFMA)
  k_att_gg<12,12,256,2,bf><<<1024, 256, 0, stream>>>(ap2, stats + 32, stats + 48, bng[1], bnb[1],
                                                     1.f/4718592.f, a3, ctrl, attf3);
  k_conv_ggm<12,256,bf><<<2048, 256, 0, stream>>>(ap2, stats + 32, stats + 48, bng[1], bnb[1],
                                                  1.f/4718592.f, attf3, btfr + 18432, ctrl,
                                                  yD, stats + 64, stats + 80);

  // L4: 10->8 (MFMA)
  k_att_gg<10,10,256,2,float><<<1024, 256, 0, stream>>>(yD, stats + 64, stats + 80, bng[2], bnb[2],
                                                        1.f/819200.f, a4, ctrl, attf3);
  k_conv_ggm<10,256,float><<<2048, 256, 0, stream>>>(yD, stats + 64, stats + 80, bng[2], bnb[2],
                                                     1.f/819200.f, attf3, btfr + 36864, ctrl,
                                                     yE, stats + 96, stats + 112);

  // L5: 8->6 (fp32, SR=1, batched x2, 512 thr)
  k_att_gg<8,8,256,2,float><<<1024, 256, 0, stream>>>(yE, stats + 96, stats + 112, bng[3], bnb[3],
                                                      1.f/524288.f, a5, ctrl, attf3);
  k_conv_gg<8,3,1,512,true,false,float><<<1024, 512, 0, stream>>>(yE, stats + 96, stats + 112,
                                                  bng[3], bnb[3], 1.f/524288.f, attf3, c5, ctrl,
                                                  yD, stats + 128, stats + 144);

  // L6: 6->4 (fp32, SR=1, batched x2, 384 thr; att batched x4)
  k_att_gg<6,6,256,4,float><<<512, 256, 0, stream>>>(yD, stats + 128, stats + 144, bng[4], bnb[4],
                                                     1.f/294912.f, a6, ctrl, attf3);
  k_conv_gg<6,3,1,384,true,false,float><<<1024, 384, 0, stream>>>(yD, stats + 128, stats + 144,
                                                  bng[4], bnb[4], 1.f/294912.f, attf3, c6, ctrl,
                                                  yE, stats + 160, stats + 176);

  // L7: 4x4 -> 1x1 + orientation group-max -> d_out (att batched x8, conv batched x2)
  k_att_gg<4,4,256,8,float><<<256, 256, 0, stream>>>(yE, stats + 160, stats + 176, bng[5], bnb[5],
                                                     1.f/131072.f, a7, ctrl, attf3);
  k_conv_gg<4,4,1,128,false,true,float><<<1024, 128, 0, stream>>>(yE, stats + 160, stats + 176,
                                                  bng[5], bnb[5], 1.f/131072.f, attf3, c7, ctrl,
                                                  d_out, (float*)nullptr, (float*)nullptr);
}

// Round 12
// 801.058 us; speedup vs baseline: 1.0151x; 1.0151x over previous
//
#include <hip/hip_runtime.h>
#include <hip/hip_bf16.h>
#include <cstddef>

typedef __hip_bfloat16 bf;
typedef __attribute__((ext_vector_type(8))) short short8x;
typedef __attribute__((ext_vector_type(4))) float f32x4;

__device__ __forceinline__ float ldv(const float* p){ return *p; }
__device__ __forceinline__ float ldv(const bf* p){ return __bfloat162float(*p); }
__device__ __forceinline__ void stv(float* p, float v){ *p = v; }
__device__ __forceinline__ void stv(bf* p, float v){ *p = __float2bfloat16(v); }
__device__ __forceinline__ float sigm(float x){ return 1.f/(1.f + __expf(-x)); }
__device__ __forceinline__ short bfbits(float v){
  __hip_bfloat16 h = __float2bfloat16(v);
  return *(short*)&h;
}

__device__ __forceinline__ float ldin(const void* p, long i, int f32){
  return f32 ? ((const float*)p)[i] : __bfloat162float(((const bf*)p)[i]);
}

// XOR-swizzle on 16B-unit index (involution; applied at write AND read).
__device__ __forceinline__ int swz(int u){ return u ^ ((u >> 3) & 7); }

template<int K>
__device__ __forceinline__ int rot_src(int r, int t){
  int u = t / K, v = t % K;
  int s1 = v*K + (K-1-u);
  int s2 = (K-1-u)*K + (K-1-v);
  int s3 = (K-1-v)*K + u;
  return r==0 ? t : (r==1 ? s1 : (r==2 ? s2 : s3));
}

// 12-tap MFMA for two m-tiles; A from swizzled LDS layout xin5[swz(g*HW+sp)][8] (g=ch/8),
// B held in registers (loaded once per nt from global btg).
// Tap/accumulation order identical to verified rounds: main 0..8 then tail 0..2, acc0 then acc1.
template<int HW_, int WIN>
__device__ __forceinline__ void conv12x2(const short* __restrict__ xin5, int b0, int b1, int lq,
                                         const short8x (&bm)[9], const short8x (&bt)[3],
                                         const int (&tdh)[3], const int (&tdw)[3],
                                         f32x4& acc0, f32x4& acc1){
  short8x A[9];
  #pragma unroll
  for (int t = 0; t < 9; ++t)
    A[t] = *(const short8x*)&xin5[swz(lq*HW_ + b0 + (t/3)*WIN + (t%3))*8];
  #pragma unroll
  for (int t = 0; t < 9; ++t)
    acc0 = __builtin_amdgcn_mfma_f32_16x16x32_bf16(A[t], bm[t], acc0, 0, 0, 0);
  #pragma unroll
  for (int tg = 0; tg < 3; ++tg){
    short8x a = *(const short8x*)&xin5[swz(4*HW_ + b0 + tdh[tg]*WIN + tdw[tg])*8];
    acc0 = __builtin_amdgcn_mfma_f32_16x16x32_bf16(a, bt[tg], acc0, 0, 0, 0);
  }
  #pragma unroll
  for (int t = 0; t < 9; ++t){
    short8x a = *(const short8x*)&xin5[swz(lq*HW_ + b1 + (t/3)*WIN + (t%3))*8];
    acc1 = __builtin_amdgcn_mfma_f32_16x16x32_bf16(a, bm[t], acc1, 0, 0, 0);
  }
  #pragma unroll
  for (int tg = 0; tg < 3; ++tg){
    short8x a = *(const short8x*)&xin5[swz(4*HW_ + b1 + tdh[tg]*WIN + tdw[tg])*8];
    acc1 = __builtin_amdgcn_mfma_f32_16x16x32_bf16(a, bt[tg], acc1, 0, 0, 0);
  }
}

// ---------------- dtype detection ----------------
__global__ void k_detect(const void* x, int* ctrl){
  int lane = threadIdx.x;
  float mx = 0.f;
  for (int i = lane; i < 2048; i += 64){
    float v = __bfloat162float(((const bf*)x)[i]);
    if (v != v) v = 1e30f;
    mx = fmaxf(mx, fabsf(v));
  }
  #pragma unroll
  for (int off = 32; off > 0; off >>= 1) mx = fmaxf(mx, __shfl_xor(mx, off));
  if (lane == 0) ctrl[0] = (mx > 1e6f) ? 1 : 0;
}

// ---------------- build MFMA B-frag buffers (tail-merged layout), 18432 shorts/layer ----------------
__global__ __launch_bounds__(256) void k_build_bt(const void* c2, const void* c3, const void* c4,
                                                  const int* __restrict__ ctrl, short* __restrict__ btg){
  const void* ws[3] = {c2, c3, c4};
  const void* cw = ws[blockIdx.x];
  short* outp = btg + blockIdx.x * 18432;
  int f32 = ctrl[0];
  for (int i = threadIdx.x; i < 18432; i += 256){
    int t, n, k;
    bool valid;
    if (i < 13824){
      t = i / 1536;
      int rem = i % 1536;
      int kq = rem / 384;
      n = (i >> 3) % 48;
      k = kq*8 + (i & 7);
      valid = (n < 40);
    } else {
      int j2 = i - 13824;
      int tg = j2 / 1536;
      int lq = (j2 % 1536) / 384;
      n = (j2 >> 3) % 48;
      k = 32 + (i & 7);
      t = tg*4 + lq;
      valid = (t < 9) && (n < 40);
    }
    float v = 0.f;
    if (valid){
      int o = n >> 2, r = n & 3, ci = k >> 2, s = k & 3;
      v = ldin(cw, ((o*10 + ci)*4 + ((s - r) & 3))*9 + rot_src<3>(r, t), f32);
    }
    outp[i] = bfbits(v);
  }
}

// ---------------- L1 fused: att1 gate + xa write + conv1 bn1-stats (512 thr) ----------------
__global__ __launch_bounds__(512) void k_l1(const void* __restrict__ x,
                                            const void* __restrict__ a1,
                                            const void* __restrict__ c1,
                                            const int* __restrict__ ctrl,
                                            float* __restrict__ xa,
                                            float* __restrict__ ssum, float* __restrict__ ssq){
  __shared__ float xs[784];
  __shared__ float ws[49];
  __shared__ float xg[28*29];
  __shared__ float wr1[360];
  __shared__ float lsum[16], lss[16];
  int b = blockIdx.x, tid = threadIdx.x;
  int f32 = ctrl[0];
  for (int i = tid; i < 784; i += 512) xs[i] = ldin(x, (long)b*784 + i, f32);
  if (tid < 49) ws[tid] = ldin(a1, tid, f32) + ldin(a1, 49 + tid, f32);
  for (int i = tid; i < 360; i += 512){
    int r = i / 90, rem = i % 90, o = rem / 9, t = rem % 9;
    wr1[i] = ldin(c1, o*9 + rot_src<3>(r, t), f32);
  }
  if (tid < 16){ lsum[tid] = 0.f; lss[tid] = 0.f; }
  __syncthreads();
  for (int p = tid; p < 784; p += 512){
    int h = p / 28, w = p % 28;
    float acc = 0.f;
    #pragma unroll
    for (int u = 0; u < 7; ++u){
      int hh = h + u - 3;
      if (hh < 0 || hh >= 28) continue;
      #pragma unroll
      for (int v = 0; v < 7; ++v){
        int ww = w + v - 3;
        if (ww < 0 || ww >= 28) continue;
        acc = fmaf(xs[hh*28 + ww], ws[u*7 + v], acc);
      }
    }
    float g = xs[p] * sigm(acc);
    xg[h*29 + w] = g;
    xa[(size_t)b*784 + p] = g;
  }
  __syncthreads();
  for (int it = tid; it < 1040; it += 512){
    int o = it / 104, rem = it % 104, r = rem / 26, h = rem % 26;
    float wt[9];
    #pragma unroll
    for (int t = 0; t < 9; ++t) wt[t] = wr1[(r*10 + o)*9 + t];
    float acc[26];
    #pragma unroll
    for (int w = 0; w < 26; ++w) acc[w] = 0.f;
    #pragma unroll
    for (int u = 0; u < 3; ++u){
      float rr[28];
      #pragma unroll
      for (int j = 0; j < 28; ++j) rr[j] = xg[(h + u)*29 + j];
      #pragma unroll
      for (int v = 0; v < 3; ++v){
        float wv = wt[u*3 + v];
        #pragma unroll
        for (int w = 0; w < 26; ++w) acc[w] = fmaf(rr[w + v], wv, acc[w]);
      }
    }
    float s1 = 0.f, s2 = 0.f;
    #pragma unroll
    for (int w = 0; w < 26; ++w){ s1 += acc[w]; s2 += acc[w]*acc[w]; }
    atomicAdd(&lsum[o], s1); atomicAdd(&lss[o], s2);
  }
  __syncthreads();
  if (tid < 10){ atomicAdd(&ssum[tid], lsum[tid]); atomicAdd(&ssq[tid], lss[tid]); }
}

// ---------------- L2 attention (2 batch items/block; finalize prologue; 13-wide half-rows) ----------------
__global__ __launch_bounds__(512) void k_att2(const float* __restrict__ xa,
                                              const void* __restrict__ c1,
                                              const float* __restrict__ psum,
                                              const float* __restrict__ psq,
                                              const void* __restrict__ g,
                                              const void* __restrict__ bb,
                                              float invN,
                                              const void* __restrict__ aw,
                                              const int* __restrict__ ctrl,
                                              float* __restrict__ attf){
  __shared__ float xs[2][28*29];
  __shared__ float wr1[360];
  __shared__ float ps[2][8*26*33];
  __shared__ float wl[1568];
  __shared__ float scs[10], shs[10];
  int b0 = blockIdx.x*2, tid = threadIdx.x;
  int f32 = ctrl[0];
  if (tid < 10){
    float m = psum[tid] * invN;
    float v = fmaxf(psq[tid] * invN - m*m, 0.f);
    float sc = ldin(g, tid, f32) * rsqrtf(v + 2e-5f);
    scs[tid] = sc;
    shs[tid] = ldin(bb, tid, f32) - m * sc;
  }
  for (int i = tid; i < 1568; i += 512){
    int bi = i / 784, p = i % 784;
    int row = p / 28, col = p % 28;
    xs[bi][row*29 + col] = xa[(size_t)(b0 + bi)*784 + p];
  }
  for (int i = tid; i < 360; i += 512){
    int r = i / 90, rem = i % 90, o = rem / 9, t = rem % 9;
    wr1[i] = ldin(c1, o*9 + rot_src<3>(r, t), f32);
  }
  for (int i = tid; i < 2*8*26*33; i += 512) ps[i / 6864][i % 6864] = 0.f;
  for (int i = tid; i < 1568; i += 512){
    int r = i / 392, rem = i % 392, i2 = rem / 196, s = (rem % 196)/49, t = rem % 49;
    int sp = (s - r) & 3;
    wl[i] = ldin(aw, (i2*4 + sp)*49 + rot_src<7>(r, t), f32);
  }
  __syncthreads();
  if (tid < 416){
    int bi = tid / 208, j = tid % 208;
    int pair = j >> 1, half = j & 1;
    int s = pair / 26, h = pair % 26;
    int w0 = half*13;
    float msum[13], mmax[13];
    #pragma unroll
    for (int w = 0; w < 13; ++w){ msum[w] = 0.f; mmax[w] = 0.f; }
    for (int o = 0; o < 10; ++o){
      const float* wb = wr1 + (s*10 + o)*9;
      float acc[13];
      #pragma unroll
      for (int w = 0; w < 13; ++w) acc[w] = 0.f;
      #pragma unroll
      for (int u = 0; u < 3; ++u){
        float rr[15];
        #pragma unroll
        for (int j2 = 0; j2 < 15; ++j2) rr[j2] = xs[bi][(h + u)*29 + w0 + j2];
        #pragma unroll
        for (int v = 0; v < 3; ++v){
          float wv = wb[u*3 + v];
          #pragma unroll
          for (int w = 0; w < 13; ++w) acc[w] = fmaf(rr[w + v], wv, acc[w]);
        }
      }
      float a_sc = scs[o], a_sh = shs[o];
      #pragma unroll
      for (int w = 0; w < 13; ++w){
        float val = fmaxf(fmaf(acc[w], a_sc, a_sh), 0.f);
        msum[w] += val; mmax[w] = fmaxf(mmax[w], val);
      }
    }
    #pragma unroll
    for (int w = 0; w < 13; ++w){
      ps[bi][s*858 + h*33 + 3 + w0 + w] = msum[w] * 0.1f;
      ps[bi][(4 + s)*858 + h*33 + 3 + w0 + w] = mmax[w];
    }
  }
  __syncthreads();
  if (tid < 416){
    int bi = tid / 208, j = tid % 208;
    int pair = j >> 1, half = j & 1;
    int r = pair / 26, h = pair % 26;
    int w0 = half*13;
    float acc[13];
    #pragma unroll
    for (int w = 0; w < 13; ++w) acc[w] = 0.f;
    for (int c = 0; c < 8; ++c){
      const float* wb = wl + r*392 + c*49;
      const float* pb = ps[bi] + c*858;
      #pragma unroll
      for (int u = 0; u < 7; ++u){
        int row = h + u - 3;
        if (row < 0 || row >= 26) continue;
        float rr[19];
        #pragma unroll
        for (int j2 = 0; j2 < 19; ++j2) rr[j2] = pb[row*33 + w0 + j2];
        #pragma unroll
        for (int v = 0; v < 7; ++v){
          float wv = wb[u*7 + v];
          #pragma unroll
          for (int w = 0; w < 13; ++w) acc[w] = fmaf(rr[w + v], wv, acc[w]);
        }
      }
    }
    size_t base = ((size_t)(b0 + bi)*4 + r)*676 + (size_t)h*26 + w0;
    #pragma unroll
    for (int w = 0; w < 13; ++w) attf[base + w] = sigm(acc[w]);
  }
}

// ---------------- L2 conv via MFMA: 512 thr (R5/R7-proven), nt-outer B-in-regs + swizzled xin5 ----------------
__global__ __launch_bounds__(512, 4) void k_conv2m(const float* __restrict__ xa,
                                                const void* __restrict__ c1,
                                                const float* __restrict__ psum,
                                                const float* __restrict__ psq,
                                                const void* __restrict__ g,
                                                const void* __restrict__ bb,
                                                float invN,
                                                const float* __restrict__ attm,
                                                const short* __restrict__ btg,
                                                const int* __restrict__ ctrl,
                                                bf* __restrict__ ap2,
                                                float* __restrict__ ssum, float* __restrict__ ssq){
  __shared__ alignas(16) float xs2[784];
  __shared__ float wr1[360];
  __shared__ alignas(16) float attL[4*676];
  __shared__ alignas(16) short xin5[3384*8];   // units padded to %8 for swizzle
  __shared__ float lsum[16], lss[16];
  __shared__ float scs[10], shs[10];
  int tid = threadIdx.x, b = blockIdx.x;
  int f32 = ctrl[0];
  if (tid < 10){
    float m = psum[tid] * invN;
    float v = fmaxf(psq[tid] * invN - m*m, 0.f);
    float sc = ldin(g, tid, f32) * rsqrtf(v + 2e-5f);
    scs[tid] = sc;
    shs[tid] = ldin(bb, tid, f32) - m * sc;
  }
  for (int i = tid; i < 784; i += 512) xs2[i] = xa[(size_t)b*784 + i];
  for (int i = tid; i < 360; i += 512){
    int r = i / 90, rem = i % 90, o = rem / 9, t = rem % 9;
    wr1[i] = ldin(c1, o*9 + rot_src<3>(r, t), f32);
  }
  for (int i = tid; i < 2704; i += 512) attL[i] = attm[(size_t)b*2704 + i];
  if (tid < 16){ lsum[tid] = 0.f; lss[tid] = 0.f; }
  __syncthreads();
  for (int it = tid; it < 1040; it += 512){
    int row = it / 40, ch = it % 40;
    int ci = ch >> 2, s = ch & 3;
    float wt[9];
    {
      const float* wb = wr1 + (s*10 + ci)*9;
      #pragma unroll
      for (int t = 0; t < 9; ++t) wt[t] = wb[t];
    }
    float sc = scs[ci], sh = shs[ci];
    float acc[26];
    #pragma unroll
    for (int w = 0; w < 26; ++w) acc[w] = 0.f;
    #pragma unroll
    for (int u = 0; u < 3; ++u){
      float rr[28];
      const float4* rp = (const float4*)(xs2 + (row + u)*28);
      #pragma unroll
      for (int j = 0; j < 7; ++j){ float4 q = rp[j]; rr[4*j]=q.x; rr[4*j+1]=q.y; rr[4*j+2]=q.z; rr[4*j+3]=q.w; }
      #pragma unroll
      for (int v = 0; v < 3; ++v){
        float wv = wt[u*3 + v];
        #pragma unroll
        for (int w = 0; w < 26; ++w) acc[w] = fmaf(rr[w + v], wv, acc[w]);
      }
    }
    const float* ap = attL + s*676 + row*26;
    int gbase = (ch >> 3)*676 + row*26;
    int c7 = ch & 7;
    #pragma unroll
    for (int w = 0; w < 26; ++w){
      float v = fmaxf(fmaf(acc[w], sc, sh), 0.f) * ap[w];
      xin5[swz(gbase + w)*8 + c7] = bfbits(v);
    }
  }
  __syncthreads();

  int wv = tid >> 6, lane = tid & 63, lm = lane & 15, lq = lane >> 4;
  short8x bmain[9], btail[3];
  int tdh[3], tdw[3];
  #pragma unroll
  for (int tg = 0; tg < 3; ++tg){
    int tap = tg*4 + lq; if (tap > 8) tap = 8;
    tdh[tg] = tap / 3; tdw[tg] = tap % 3;
  }
  int curNt = -1, n = 0, o = 0;
  for (int u = wv; u < 54; u += 8){
    int nt = u / 18, mp = u % 18;
    if (nt != curNt){
      curNt = nt; n = nt*16 + lm; o = n >> 2;
      #pragma unroll
      for (int t = 0; t < 9; ++t)
        bmain[t] = *(const short8x*)(btg + (((t*4 + lq)*48 + n) << 3));
      #pragma unroll
      for (int tg = 0; tg < 3; ++tg)
        btail[tg] = *(const short8x*)(btg + 13824 + (((tg*4 + lq)*48 + n) << 3));
    }
    int mt0 = mp*2, mt1 = mp*2 + 1;
    int mA0 = mt0*16 + lm, mA1 = mt1*16 + lm;
    int qi0 = mA0 >> 2, sub0 = mA0 & 3;
    int h00 = 2*(qi0/12) + (sub0 >> 1), w00 = 2*(qi0%12) + (sub0 & 1);
    int qi1 = mA1 >> 2, sub1 = mA1 & 3;
    int h01 = 2*(qi1/12) + (sub1 >> 1), w01 = 2*(qi1%12) + (sub1 & 1);
    f32x4 acc0 = {0.f,0.f,0.f,0.f}, acc1 = {0.f,0.f,0.f,0.f};
    conv12x2<676,26>(xin5, h00*26 + w00, h01*26 + w01, lq, bmain, btail, tdh, tdw, acc0, acc1);
    if (n < 40){
      float s1 = acc0[0]+acc0[1]+acc0[2]+acc0[3] + acc1[0]+acc1[1]+acc1[2]+acc1[3];
      float s2 = acc0[0]*acc0[0]+acc0[1]*acc0[1]+acc0[2]*acc0[2]+acc0[3]*acc0[3]
               + acc1[0]*acc1[0]+acc1[1]*acc1[1]+acc1[2]*acc1[2]+acc1[3]*acc1[3];
      atomicAdd(&lsum[o], s1); atomicAdd(&lss[o], s2);
      float mx0 = fmaxf(fmaxf(acc0[0], acc0[1]), fmaxf(acc0[2], acc0[3]));
      float mx1 = fmaxf(fmaxf(acc1[0], acc1[1]), fmaxf(acc1[2], acc1[3]));
      size_t pbase = ((size_t)b*40 + n)*144;
      stv(ap2 + pbase + mt0*4 + lq, mx0);
      stv(ap2 + pbase + mt1*4 + lq, mx1);
    }
  }
  __syncthreads();
  if (tid < 10){ atomicAdd(&ssum[tid], lsum[tid]); atomicAdd(&ssq[tid], lss[tid]); }
}

// ---------------- generic GG conv via MFMA (L3/L4): coalesced staging + nt-outer B-in-regs ----------------
template<int HIN, int NT, typename TI>
__global__ __launch_bounds__(NT) void k_conv_ggm(const TI* __restrict__ act,
                                                 const float* __restrict__ psum,
                                                 const float* __restrict__ psq,
                                                 const void* __restrict__ g,
                                                 const void* __restrict__ bb,
                                                 float invN,
                                                 const float* __restrict__ attm,
                                                 const short* __restrict__ btg,
                                                 const int* __restrict__ ctrl,
                                                 float* __restrict__ out,
                                                 float* __restrict__ ssum, float* __restrict__ ssq){
  constexpr int WIN = HIN, HOUT = HIN - 2, WOUT = WIN - 2;
  constexpr int M = HOUT*WOUT, HW = HIN*WIN;
  constexpr int MT = (M + 15)/16, MU = (MT + 1)/2, UNITS = MU*3;
  constexpr int NWV = NT/64;
  constexpr int UP = ((5*HW + 7)/8)*8;
  __shared__ alignas(16) short xin5[UP*8];
  __shared__ float lsum[16], lss[16];
  __shared__ float scs[10], shs[10];
  int tid = threadIdx.x, b = blockIdx.x;
  int f32 = ctrl[0];
  if (tid < 10){
    float m = psum[tid]*invN;
    float v = fmaxf(psq[tid]*invN - m*m, 0.f);
    float sc = ldin(g, tid, f32)*rsqrtf(v + 2e-5f);
    scs[tid] = sc; shs[tid] = ldin(bb, tid, f32) - m*sc;
  }
  if (tid < 16){ lsum[tid] = 0.f; lss[tid] = 0.f; }
  __syncthreads();
  // coalesced: consecutive lanes -> consecutive sp within one channel
  for (int i = tid; i < HW*40; i += NT){
    int ch = i / HW, sp = i % HW;
    int ci = ch >> 2, s = ch & 3;
    float a = ldv(act + ((size_t)b*40 + ch)*HW + sp);
    a = fmaxf(fmaf(a, scs[ci], shs[ci]), 0.f);
    float v = a * attm[((size_t)b*4 + s)*HW + sp];
    xin5[swz((ch >> 3)*HW + sp)*8 + (ch & 7)] = bfbits(v);
  }
  __syncthreads();
  int wv = tid >> 6, lane = tid & 63, lm = lane & 15, lq = lane >> 4;
  short8x bmain[9], btail[3];
  int tdh[3], tdw[3];
  #pragma unroll
  for (int tg = 0; tg < 3; ++tg){
    int tap = tg*4 + lq; if (tap > 8) tap = 8;
    tdh[tg] = tap / 3; tdw[tg] = tap % 3;
  }
  int curNt = -1, n = 0, o = 0;
  for (int u = wv; u < UNITS; u += NWV){
    int nt = u / MU, mu = u % MU;
    if (nt != curNt){
      curNt = nt; n = nt*16 + lm; o = n >> 2;
      #pragma unroll
      for (int t = 0; t < 9; ++t)
        bmain[t] = *(const short8x*)(btg + (((t*4 + lq)*48 + n) << 3));
      #pragma unroll
      for (int tg = 0; tg < 3; ++tg)
        btail[tg] = *(const short8x*)(btg + 13824 + (((tg*4 + lq)*48 + n) << 3));
    }
    int mt0 = mu*2, mt1 = mu*2 + 1;
    int mA0 = mt0*16 + lm; if (mA0 > M-1) mA0 = M-1;
    int mA1 = mt1*16 + lm; if (mA1 > M-1) mA1 = M-1;
    int base0 = (mA0 / WOUT)*WIN + (mA0 % WOUT);
    int base1 = (mA1 / WOUT)*WIN + (mA1 % WOUT);
    f32x4 acc0 = {0.f,0.f,0.f,0.f}, acc1 = {0.f,0.f,0.f,0.f};
    conv12x2<HW,WIN>(xin5, base0, base1, lq, bmain, btail, tdh, tdw, acc0, acc1);
    if (n < 40){
      float s1 = 0.f, s2 = 0.f;
      size_t obase = ((size_t)b*40 + n)*M;
      #pragma unroll
      for (int reg = 0; reg < 4; ++reg){
        int m0 = mt0*16 + lq*4 + reg;
        if (m0 < M){ float v = acc0[reg]; s1 += v; s2 += v*v; out[obase + m0] = v; }
        int m1 = mt1*16 + lq*4 + reg;
        if (m1 < M){ float v = acc1[reg]; s1 += v; s2 += v*v; out[obase + m1] = v; }
      }
      atomicAdd(&lsum[o], s1); atomicAdd(&lss[o], s2);
    }
  }
  __syncthreads();
  if (tid < 10){ atomicAdd(&ssum[tid], lsum[tid]); atomicAdd(&ssq[tid], lss[tid]); }
}

// ---------------- generic GG spatial attention (L3..L7): 2 batch items per block ----------------
template<int H, int W, int NT, typename TA>
__global__ __launch_bounds__(NT) void k_att_gg(const TA* __restrict__ act,
                                               const float* __restrict__ psum,
                                               const float* __restrict__ psq,
                                               const void* __restrict__ g,
                                               const void* __restrict__ bb,
                                               float invN,
                                               const void* __restrict__ aw,
                                               const int* __restrict__ ctrl,
                                               float* __restrict__ att){
  constexpr int WG = (W + 6) | 1;
  constexpr int HW = H*W;
  constexpr int WH = W/2;
  constexpr int PSN = 8*H*WG;
  __shared__ float ps[2][PSN];
  __shared__ float wl[1568];
  __shared__ float scs[10], shs[10];
  int b0 = blockIdx.x*2, tid = threadIdx.x;
  int f32 = ctrl[0];
  if (tid < 10){
    float m = psum[tid]*invN;
    float v = fmaxf(psq[tid]*invN - m*m, 0.f);
    float sc = ldin(g, tid, f32)*rsqrtf(v + 2e-5f);
    scs[tid] = sc; shs[tid] = ldin(bb, tid, f32) - m*sc;
  }
  for (int i = tid; i < 1568; i += NT){
    int r = i / 392, rem = i % 392, i2 = rem / 196, s = (rem % 196)/49, t = rem % 49;
    int sp = (s - r) & 3;
    wl[i] = ldin(aw, (i2*4 + sp)*49 + rot_src<7>(r, t), f32);
  }
  __syncthreads();
  for (int i = tid; i < 2*4*H*WG; i += NT){
    int bi = i / (4*H*WG), rem0 = i % (4*H*WG);
    int b = b0 + bi;
    int s = rem0 / (H*WG), rem = rem0 % (H*WG), row = rem / WG, col = rem % WG;
    int cc = col - 3;
    float mn = 0.f, mx = 0.f;
    if (cc >= 0 && cc < W){
      float sum = 0.f; mx = 0.f;
      const TA* ap = act + (size_t)b*40*HW + (size_t)s*HW + row*W + cc;
      #pragma unroll
      for (int c = 0; c < 10; ++c){
        float v = fmaxf(fmaf(ldv(ap + (size_t)c*4*HW), scs[c], shs[c]), 0.f);
        sum += v; mx = fmaxf(mx, v);
      }
      mn = sum * 0.1f;
    }
    ps[bi][s*H*WG + row*WG + col] = mn;
    ps[bi][(4 + s)*H*WG + row*WG + col] = mx;
  }
  __syncthreads();
  for (int it = tid; it < 2*8*H; it += NT){
    int bi = it / (8*H), rem0 = it % (8*H);
    int b = b0 + bi;
    int r = rem0 / (2*H), rem2 = rem0 % (2*H), h = rem2 >> 1, half = rem2 & 1;
    int w0 = half*WH;
    float acc[WH];
    #pragma unroll
    for (int w = 0; w < WH; ++w) acc[w] = 0.f;
    for (int c = 0; c < 8; ++c){
      const float* wb = wl + r*392 + c*49;
      const float* pb = ps[bi] + c*H*WG;
      #pragma unroll
      for (int u = 0; u < 7; ++u){
        int row = h + u - 3;
        if (row < 0 || row >= H) continue;
        float rr[WH + 6];
        #pragma unroll
        for (int j = 0; j < WH + 6; ++j) rr[j] = pb[row*WG + w0 + j];
        #pragma unroll
        for (int v = 0; v < 7; ++v){
          float wv = wb[u*7 + v];
          #pragma unroll
          for (int w = 0; w < WH; ++w) acc[w] = fmaf(rr[w + v], wv, acc[w]);
        }
      }
    }
    size_t base = ((size_t)b*4 + r)*HW + (size_t)h*W + w0;
    #pragma unroll
    for (int w = 0; w < WH; ++w) att[base + w] = sigm(acc[w]);
  }
}

// ---------------- fp32 GG conv (L5..L7): 2 batch items per block ----------------
template<int HIN, int K, int SR, int NT, bool STATS, bool FINAL, typename TI>
__global__ __launch_bounds__(NT) void k_conv_gg(const TI* __restrict__ act,
                                                const float* __restrict__ psum,
                                                const float* __restrict__ psq,
                                                const void* __restrict__ g,
                                                const void* __restrict__ bb,
                                                float invN,
                                                const float* __restrict__ attm,
                                                const void* __restrict__ cw,
                                                const int* __restrict__ ctrl,
                                                void* __restrict__ out,
                                                float* __restrict__ ssum, float* __restrict__ ssq){
  constexpr int WIN  = HIN;
  constexpr int HOUT = HIN - K + 1;
  constexpr int WOUT = WIN - K + 1;
  constexpr int NS   = HOUT / SR;
  constexpr int WP   = WIN | 1;
  constexpr int NW   = 10*10*4*K*K;
  constexpr int HW   = HIN*WIN;
  constexpr int XN   = 40*HIN*WP;
  __shared__ float xin[2][XN];
  __shared__ float wl[NW];
  __shared__ float lsum[16], lss[16];
  __shared__ float scs[10], shs[10];
  __shared__ float red[2][48];
  int tid = threadIdx.x;
  int b0 = blockIdx.x*2;
  int f32 = ctrl[0];
  if (tid < 10){
    float m = psum[tid]*invN;
    float v = fmaxf(psq[tid]*invN - m*m, 0.f);
    float sc = ldin(g, tid, f32)*rsqrtf(v + 2e-5f);
    scs[tid] = sc; shs[tid] = ldin(bb, tid, f32) - m*sc;
  }
  if (STATS && tid < 16){ lsum[tid] = 0.f; lss[tid] = 0.f; }
  for (int i = tid; i < NW; i += NT) wl[i] = ldin(cw, i, f32);
  __syncthreads();
  for (int i = tid; i < 2*XN; i += NT){
    int bi = i / XN, rem0 = i % XN;
    int b = b0 + bi;
    int c = rem0 / (HIN*WP), rem = rem0 % (HIN*WP), rr = rem / WP, col = rem % WP;
    float v = 0.f;
    if (col < WIN){
      int ch = c >> 2, s = c & 3;
      float a = ldv(act + ((size_t)b*40 + c)*HW + (size_t)rr*WIN + col);
      a = fmaxf(fmaf(a, scs[ch], shs[ch]), 0.f);
      v = a * attm[((size_t)b*4 + s)*HW + (size_t)rr*WIN + col];
    }
    xin[bi][rem0] = v;
  }
  __syncthreads();
  for (int it = tid; it < 2*40*NS; it += NT){
    int bi = it / (40*NS), rem0 = it % (40*NS);
    int b = b0 + bi;
    int o = rem0 / (4*NS), rem = rem0 % (4*NS), r = rem / NS, hs = rem % NS;
    int h0 = hs * SR;
    int perm[K*K];
    #pragma unroll
    for (int t = 0; t < K*K; ++t) perm[t] = rot_src<K>(r, t);
    float acc[SR][WOUT];
    #pragma unroll
    for (int a = 0; a < SR; ++a)
      #pragma unroll
      for (int w = 0; w < WOUT; ++w) acc[a][w] = 0.f;
    for (int ci = 0; ci < 10; ++ci){
      #pragma unroll
      for (int s = 0; s < 4; ++s){
        int sp = (s - r) & 3;
        const float* wb = wl + (size_t)((o*10 + ci)*4 + sp)*K*K;
        float wt[K*K];
        #pragma unroll
        for (int t = 0; t < K*K; ++t) wt[t] = wb[perm[t]];
        const float* ib = xin[bi] + (ci*4 + s)*HIN*WP;
        #pragma unroll
        for (int ri = 0; ri < SR + K - 1; ++ri){
          float rr3[WP];
          #pragma unroll
          for (int j = 0; j < WP; ++j) rr3[j] = ib[(h0 + ri)*WP + j];
          #pragma unroll
          for (int u = 0; u < K; ++u){
            int orr = ri - u;
            if (orr < 0 || orr >= SR) continue;
            #pragma unroll
            for (int v = 0; v < K; ++v){
              float wv = wt[u*K + v];
              #pragma unroll
              for (int w = 0; w < WOUT; ++w) acc[orr][w] = fmaf(rr3[w + v], wv, acc[orr][w]);
            }
          }
        }
      }
    }
    if constexpr (STATS){
      float s1 = 0.f, s2 = 0.f;
      #pragma unroll
      for (int a = 0; a < SR; ++a)
        #pragma unroll
        for (int w = 0; w < WOUT; ++w){ s1 += acc[a][w]; s2 += acc[a][w]*acc[a][w]; }
      atomicAdd(&lsum[o], s1); atomicAdd(&lss[o], s2);
    }
    if constexpr (FINAL){
      red[bi][o*4 + r] = acc[0][0];
    } else {
      #pragma unroll
      for (int a = 0; a < SR; ++a){
        size_t base = ((size_t)b*40 + o*4 + r)*HOUT*WOUT + (size_t)(h0 + a)*WOUT;
        #pragma unroll
        for (int w = 0; w < WOUT; ++w) ((float*)out)[base + w] = acc[a][w];
      }
    }
  }
  if constexpr (STATS){
    __syncthreads();
    if (tid < 10){ atomicAdd(&ssum[tid], lsum[tid]); atomicAdd(&ssq[tid], lss[tid]); }
  }
  if constexpr (FINAL){
    __syncthreads();
    if (tid < 20){
      int bi = tid / 10, c = tid % 10;
      float m4 = fmaxf(fmaxf(red[bi][c*4], red[bi][c*4+1]), fmaxf(red[bi][c*4+2], red[bi][c*4+3]));
      if (f32) ((float*)out)[(size_t)(b0 + bi)*10 + c] = m4;
      else stv((bf*)out + (size_t)(b0 + bi)*10 + c, m4);
    }
  }
}

extern "C" void kernel_launch(void* const* d_in, const int* in_sizes, int n_in,
                              void* d_out, int out_size, void* d_ws, size_t ws_size,
                              hipStream_t stream){
  (void)in_sizes; (void)n_in; (void)out_size; (void)ws_size;
  const void* x  = d_in[0];
  const void* c1 = d_in[1];
  const void* a1 = d_in[2];
  const void* c2 = d_in[3];
  const void* a2 = d_in[4];
  const void* c3 = d_in[5];
  const void* a3 = d_in[6];
  const void* c4 = d_in[7];
  const void* a4 = d_in[8];
  const void* c5 = d_in[9];
  const void* a5 = d_in[10];
  const void* c6 = d_in[11];
  const void* a6 = d_in[12];
  const void* c7 = d_in[13];
  const void* a7 = d_in[14];
  const void* bng[6] = {d_in[15],d_in[17],d_in[19],d_in[21],d_in[23],d_in[25]};
  const void* bnb[6] = {d_in[16],d_in[18],d_in[20],d_in[22],d_in[24],d_in[26]};

  // ---- arena ----
  size_t off = 0;
  char* wsb = (char*)d_ws;
  auto alloc = [&](size_t bytes)->void*{ void* p = wsb + off; off += (bytes + 255) & ~(size_t)255; return p; };
  int*   ctrl   = (int*)alloc(256);
  float* stats  = (float*)alloc(192*sizeof(float));
  float* scales = (float*)alloc(192*sizeof(float));
  (void)scales;
  short* btfr   = (short*)alloc(3*18432*2);
  char*  region1 = (char*)alloc(28573696);
  bf*    ap2 = (bf*)alloc((size_t)2048*40*144*2);
  float* yD  = (float*)alloc((size_t)2048*40*100*4);
  float* xa    = (float*)region1;
  float* attf2 = (float*)(region1 + 6422528);
  float* yE    = (float*)region1;
  float* attf3 = (float*)(region1 + 20971520);

  hipMemsetAsync(ctrl, 0, 1024, stream);
  k_detect<<<1, 64, 0, stream>>>(x, ctrl);
  k_build_bt<<<3, 256, 0, stream>>>(c2, c3, c4, ctrl, btfr);

  // L1
  k_l1<<<2048, 512, 0, stream>>>(x, a1, c1, ctrl, xa, stats + 0, stats + 16);

  // L2 (bn1 finalize fused in consumers; att2 2 items/block)
  k_att2<<<1024, 512, 0, stream>>>(xa, c1, stats + 0, stats + 16, bng[0], bnb[0],
                                   1.f/5537792.f, a2, ctrl, attf2);
  k_conv2m<<<2048, 512, 0, stream>>>(xa, c1, stats + 0, stats + 16, bng[0], bnb[0],
                                     1.f/5537792.f, attf2, btfr, ctrl, ap2, stats + 32, stats + 48);

  // L3: 12->10 (MFMA)
  k_att_gg<12,12,256,bf><<<1024, 256, 0, stream>>>(ap2, stats + 32, stats + 48, bng[1], bnb[1],
                                                   1.f/4718592.f, a3, ctrl, attf3);
  k_conv_ggm<12,256,bf><<<2048, 256, 0, stream>>>(ap2, stats + 32, stats + 48, bng[1], bnb[1],
                                                  1.f/4718592.f, attf3, btfr + 18432, ctrl,
                                                  yD, stats + 64, stats + 80);

  // L4: 10->8 (MFMA)
  k_att_gg<10,10,256,float><<<1024, 256, 0, stream>>>(yD, stats + 64, stats + 80, bng[2], bnb[2],
                                                      1.f/819200.f, a4, ctrl, attf3);
  k_conv_ggm<10,256,float><<<2048, 256, 0, stream>>>(yD, stats + 64, stats + 80, bng[2], bnb[2],
                                                     1.f/819200.f, attf3, btfr + 36864, ctrl,
                                                     yE, stats + 96, stats + 112);

  // L5: 8->6 (fp32, SR=1, batched x2, 512 thr)
  k_att_gg<8,8,256,float><<<1024, 256, 0, stream>>>(yE, stats + 96, stats + 112, bng[3], bnb[3],
                                                    1.f/524288.f, a5, ctrl, attf3);
  k_conv_gg<8,3,1,512,true,false,float><<<1024, 512, 0, stream>>>(yE, stats + 96, stats + 112,
                                                  bng[3], bnb[3], 1.f/524288.f, attf3, c5, ctrl,
                                                  yD, stats + 128, stats + 144);

  // L6: 6->4 (fp32, SR=1, batched x2, 384 thr)
  k_att_gg<6,6,256,float><<<1024, 256, 0, stream>>>(yD, stats + 128, stats + 144, bng[4], bnb[4],
                                                    1.f/294912.f, a6, ctrl, attf3);
  k_conv_gg<6,3,1,384,true,false,float><<<1024, 384, 0, stream>>>(yD, stats + 128, stats + 144,
                                                  bng[4], bnb[4], 1.f/294912.f, attf3, c6, ctrl,
                                                  yE, stats + 160, stats + 176);

  // L7: 4x4 -> 1x1 + orientation group-max -> d_out (batched x2, 128 thr)
  k_att_gg<4,4,256,float><<<1024, 256, 0, stream>>>(yE, stats + 160, stats + 176, bng[5], bnb[5],
                                                    1.f/131072.f, a7, ctrl, attf3);
  k_conv_gg<4,4,1,128,false,true,float><<<1024, 128, 0, stream>>>(yE, stats + 160, stats + 176,
                                                  bng[5], bnb[5], 1.f/131072.f, attf3, c7, ctrl,
                                                  d_out, (float*)nullptr, (float*)nullptr);
}

// Round 13
// 795.293 us; speedup vs baseline: 1.0225x; 1.0072x over previous
//
#include <hip/hip_runtime.h>
#include <hip/hip_bf16.h>
#include <cstddef>

typedef __hip_bfloat16 bf;
typedef __attribute__((ext_vector_type(8))) short short8x;
typedef __attribute__((ext_vector_type(4))) float f32x4;

__device__ __forceinline__ float ldv(const float* p){ return *p; }
__device__ __forceinline__ float ldv(const bf* p){ return __bfloat162float(*p); }
__device__ __forceinline__ void stv(float* p, float v){ *p = v; }
__device__ __forceinline__ void stv(bf* p, float v){ *p = __float2bfloat16(v); }
__device__ __forceinline__ float sigm(float x){ return 1.f/(1.f + __expf(-x)); }
__device__ __forceinline__ short bfbits(float v){
  __hip_bfloat16 h = __float2bfloat16(v);
  return *(short*)&h;
}

__device__ __forceinline__ float ldin(const void* p, long i, int f32){
  return f32 ? ((const float*)p)[i] : __bfloat162float(((const bf*)p)[i]);
}

// XOR-swizzle on 16B-unit index (involution; applied at write AND read).
__device__ __forceinline__ int swz(int u){ return u ^ ((u >> 3) & 7); }

template<int K>
__device__ __forceinline__ int rot_src(int r, int t){
  int u = t / K, v = t % K;
  int s1 = v*K + (K-1-u);
  int s2 = (K-1-u)*K + (K-1-v);
  int s3 = (K-1-v)*K + u;
  return r==0 ? t : (r==1 ? s1 : (r==2 ? s2 : s3));
}

// 12-tap MFMA for two m-tiles; A from swizzled LDS layout xin5[swz(g*HW+sp)][8] (g=ch/8),
// B held in registers (loaded once per nt from global btg).
// Tap/accumulation order identical to verified rounds: main 0..8 then tail 0..2, acc0 then acc1.
template<int HW_, int WIN>
__device__ __forceinline__ void conv12x2(const short* __restrict__ xin5, int b0, int b1, int lq,
                                         const short8x (&bm)[9], const short8x (&bt)[3],
                                         const int (&tdh)[3], const int (&tdw)[3],
                                         f32x4& acc0, f32x4& acc1){
  short8x A[9];
  #pragma unroll
  for (int t = 0; t < 9; ++t)
    A[t] = *(const short8x*)&xin5[swz(lq*HW_ + b0 + (t/3)*WIN + (t%3))*8];
  #pragma unroll
  for (int t = 0; t < 9; ++t)
    acc0 = __builtin_amdgcn_mfma_f32_16x16x32_bf16(A[t], bm[t], acc0, 0, 0, 0);
  #pragma unroll
  for (int tg = 0; tg < 3; ++tg){
    short8x a = *(const short8x*)&xin5[swz(4*HW_ + b0 + tdh[tg]*WIN + tdw[tg])*8];
    acc0 = __builtin_amdgcn_mfma_f32_16x16x32_bf16(a, bt[tg], acc0, 0, 0, 0);
  }
  #pragma unroll
  for (int t = 0; t < 9; ++t){
    short8x a = *(const short8x*)&xin5[swz(lq*HW_ + b1 + (t/3)*WIN + (t%3))*8];
    acc1 = __builtin_amdgcn_mfma_f32_16x16x32_bf16(a, bm[t], acc1, 0, 0, 0);
  }
  #pragma unroll
  for (int tg = 0; tg < 3; ++tg){
    short8x a = *(const short8x*)&xin5[swz(4*HW_ + b1 + tdh[tg]*WIN + tdw[tg])*8];
    acc1 = __builtin_amdgcn_mfma_f32_16x16x32_bf16(a, bt[tg], acc1, 0, 0, 0);
  }
}

// ---------------- dtype detection ----------------
__global__ void k_detect(const void* x, int* ctrl){
  int lane = threadIdx.x;
  float mx = 0.f;
  for (int i = lane; i < 2048; i += 64){
    float v = __bfloat162float(((const bf*)x)[i]);
    if (v != v) v = 1e30f;
    mx = fmaxf(mx, fabsf(v));
  }
  #pragma unroll
  for (int off = 32; off > 0; off >>= 1) mx = fmaxf(mx, __shfl_xor(mx, off));
  if (lane == 0) ctrl[0] = (mx > 1e6f) ? 1 : 0;
}

// ---------------- build MFMA B-frag buffers (tail-merged layout), 18432 shorts/layer ----------------
__global__ __launch_bounds__(256) void k_build_bt(const void* c2, const void* c3, const void* c4,
                                                  const int* __restrict__ ctrl, short* __restrict__ btg){
  const void* ws[3] = {c2, c3, c4};
  const void* cw = ws[blockIdx.x];
  short* outp = btg + blockIdx.x * 18432;
  int f32 = ctrl[0];
  for (int i = threadIdx.x; i < 18432; i += 256){
    int t, n, k;
    bool valid;
    if (i < 13824){
      t = i / 1536;
      int rem = i % 1536;
      int kq = rem / 384;
      n = (i >> 3) % 48;
      k = kq*8 + (i & 7);
      valid = (n < 40);
    } else {
      int j2 = i - 13824;
      int tg = j2 / 1536;
      int lq = (j2 % 1536) / 384;
      n = (j2 >> 3) % 48;
      k = 32 + (i & 7);
      t = tg*4 + lq;
      valid = (t < 9) && (n < 40);
    }
    float v = 0.f;
    if (valid){
      int o = n >> 2, r = n & 3, ci = k >> 2, s = k & 3;
      v = ldin(cw, ((o*10 + ci)*4 + ((s - r) & 3))*9 + rot_src<3>(r, t), f32);
    }
    outp[i] = bfbits(v);
  }
}

// ---------------- L1 fused: att1 gate + xa write + conv1 bn1-stats (512 thr) ----------------
__global__ __launch_bounds__(512) void k_l1(const void* __restrict__ x,
                                            const void* __restrict__ a1,
                                            const void* __restrict__ c1,
                                            const int* __restrict__ ctrl,
                                            float* __restrict__ xa,
                                            float* __restrict__ ssum, float* __restrict__ ssq){
  __shared__ float xs[784];
  __shared__ float ws[49];
  __shared__ float xg[28*29];
  __shared__ float wr1[360];
  __shared__ float lsum[16], lss[16];
  int b = blockIdx.x, tid = threadIdx.x;
  int f32 = ctrl[0];
  for (int i = tid; i < 784; i += 512) xs[i] = ldin(x, (long)b*784 + i, f32);
  if (tid < 49) ws[tid] = ldin(a1, tid, f32) + ldin(a1, 49 + tid, f32);
  for (int i = tid; i < 360; i += 512){
    int r = i / 90, rem = i % 90, o = rem / 9, t = rem % 9;
    wr1[i] = ldin(c1, o*9 + rot_src<3>(r, t), f32);
  }
  if (tid < 16){ lsum[tid] = 0.f; lss[tid] = 0.f; }
  __syncthreads();
  for (int p = tid; p < 784; p += 512){
    int h = p / 28, w = p % 28;
    float acc = 0.f;
    #pragma unroll
    for (int u = 0; u < 7; ++u){
      int hh = h + u - 3;
      if (hh < 0 || hh >= 28) continue;
      #pragma unroll
      for (int v = 0; v < 7; ++v){
        int ww = w + v - 3;
        if (ww < 0 || ww >= 28) continue;
        acc = fmaf(xs[hh*28 + ww], ws[u*7 + v], acc);
      }
    }
    float g = xs[p] * sigm(acc);
    xg[h*29 + w] = g;
    xa[(size_t)b*784 + p] = g;
  }
  __syncthreads();
  for (int it = tid; it < 1040; it += 512){
    int o = it / 104, rem = it % 104, r = rem / 26, h = rem % 26;
    float wt[9];
    #pragma unroll
    for (int t = 0; t < 9; ++t) wt[t] = wr1[(r*10 + o)*9 + t];
    float acc[26];
    #pragma unroll
    for (int w = 0; w < 26; ++w) acc[w] = 0.f;
    #pragma unroll
    for (int u = 0; u < 3; ++u){
      float rr[28];
      #pragma unroll
      for (int j = 0; j < 28; ++j) rr[j] = xg[(h + u)*29 + j];
      #pragma unroll
      for (int v = 0; v < 3; ++v){
        float wv = wt[u*3 + v];
        #pragma unroll
        for (int w = 0; w < 26; ++w) acc[w] = fmaf(rr[w + v], wv, acc[w]);
      }
    }
    float s1 = 0.f, s2 = 0.f;
    #pragma unroll
    for (int w = 0; w < 26; ++w){ s1 += acc[w]; s2 += acc[w]*acc[w]; }
    atomicAdd(&lsum[o], s1); atomicAdd(&lss[o], s2);
  }
  __syncthreads();
  if (tid < 10){ atomicAdd(&ssum[tid], lsum[tid]); atomicAdd(&ssq[tid], lss[tid]); }
}

// ---------------- L2 attention (finalize prologue; 256 threads, 13-wide half-rows) ----------------
__global__ __launch_bounds__(256) void k_att2(const float* __restrict__ xa,
                                              const void* __restrict__ c1,
                                              const float* __restrict__ psum,
                                              const float* __restrict__ psq,
                                              const void* __restrict__ g,
                                              const void* __restrict__ bb,
                                              float invN,
                                              const void* __restrict__ aw,
                                              const int* __restrict__ ctrl,
                                              float* __restrict__ attf){
  __shared__ float xs[28*29];
  __shared__ float wr1[360];
  __shared__ float ps[8*26*33];
  __shared__ float wl[1568];
  __shared__ float scs[10], shs[10];
  int b = blockIdx.x, tid = threadIdx.x;
  int f32 = ctrl[0];
  if (tid < 10){
    float m = psum[tid] * invN;
    float v = fmaxf(psq[tid] * invN - m*m, 0.f);
    float sc = ldin(g, tid, f32) * rsqrtf(v + 2e-5f);
    scs[tid] = sc;
    shs[tid] = ldin(bb, tid, f32) - m * sc;
  }
  for (int i = tid; i < 784; i += 256){
    int row = i / 28, col = i % 28;
    xs[row*29 + col] = xa[(size_t)b*784 + i];
  }
  for (int i = tid; i < 360; i += 256){
    int r = i / 90, rem = i % 90, o = rem / 9, t = rem % 9;
    wr1[i] = ldin(c1, o*9 + rot_src<3>(r, t), f32);
  }
  for (int i = tid; i < 8*26*33; i += 256) ps[i] = 0.f;
  for (int i = tid; i < 1568; i += 256){
    int r = i / 392, rem = i % 392, i2 = rem / 196, s = (rem % 196)/49, t = rem % 49;
    int sp = (s - r) & 3;
    wl[i] = ldin(aw, (i2*4 + sp)*49 + rot_src<7>(r, t), f32);
  }
  __syncthreads();
  if (tid < 208){
    int pair = tid >> 1, half = tid & 1;
    int s = pair / 26, h = pair % 26;
    int w0 = half*13;
    float msum[13], mmax[13];
    #pragma unroll
    for (int w = 0; w < 13; ++w){ msum[w] = 0.f; mmax[w] = 0.f; }
    for (int o = 0; o < 10; ++o){
      const float* wb = wr1 + (s*10 + o)*9;
      float acc[13];
      #pragma unroll
      for (int w = 0; w < 13; ++w) acc[w] = 0.f;
      #pragma unroll
      for (int u = 0; u < 3; ++u){
        float rr[15];
        #pragma unroll
        for (int j = 0; j < 15; ++j) rr[j] = xs[(h + u)*29 + w0 + j];
        #pragma unroll
        for (int v = 0; v < 3; ++v){
          float wv = wb[u*3 + v];
          #pragma unroll
          for (int w = 0; w < 13; ++w) acc[w] = fmaf(rr[w + v], wv, acc[w]);
        }
      }
      float a_sc = scs[o], a_sh = shs[o];
      #pragma unroll
      for (int w = 0; w < 13; ++w){
        float val = fmaxf(fmaf(acc[w], a_sc, a_sh), 0.f);
        msum[w] += val; mmax[w] = fmaxf(mmax[w], val);
      }
    }
    #pragma unroll
    for (int w = 0; w < 13; ++w){
      ps[s*858 + h*33 + 3 + w0 + w] = msum[w] * 0.1f;
      ps[(4 + s)*858 + h*33 + 3 + w0 + w] = mmax[w];
    }
  }
  __syncthreads();
  if (tid < 208){
    int pair = tid >> 1, half = tid & 1;
    int r = pair / 26, h = pair % 26;
    int w0 = half*13;
    float acc[13];
    #pragma unroll
    for (int w = 0; w < 13; ++w) acc[w] = 0.f;
    for (int c = 0; c < 8; ++c){
      const float* wb = wl + r*392 + c*49;
      const float* pb = ps + c*858;
      #pragma unroll
      for (int u = 0; u < 7; ++u){
        int row = h + u - 3;
        if (row < 0 || row >= 26) continue;
        float rr[19];
        #pragma unroll
        for (int j = 0; j < 19; ++j) rr[j] = pb[row*33 + w0 + j];
        #pragma unroll
        for (int v = 0; v < 7; ++v){
          float wv = wb[u*7 + v];
          #pragma unroll
          for (int w = 0; w < 13; ++w) acc[w] = fmaf(rr[w + v], wv, acc[w]);
        }
      }
    }
    size_t base = ((size_t)b*4 + r)*676 + (size_t)h*26 + w0;
    #pragma unroll
    for (int w = 0; w < 13; ++w) attf[base + w] = sigm(acc[w]);
  }
}

// ---------------- L2 conv via MFMA: 512 thr (R5/R7-proven), nt-outer B-in-regs + swizzled xin5 ----------------
__global__ __launch_bounds__(512, 4) void k_conv2m(const float* __restrict__ xa,
                                                const void* __restrict__ c1,
                                                const float* __restrict__ psum,
                                                const float* __restrict__ psq,
                                                const void* __restrict__ g,
                                                const void* __restrict__ bb,
                                                float invN,
                                                const float* __restrict__ attm,
                                                const short* __restrict__ btg,
                                                const int* __restrict__ ctrl,
                                                bf* __restrict__ ap2,
                                                float* __restrict__ ssum, float* __restrict__ ssq){
  __shared__ alignas(16) float xs2[784];
  __shared__ float wr1[360];
  __shared__ alignas(16) float attL[4*676];
  __shared__ alignas(16) short xin5[3384*8];   // units padded to %8 for swizzle
  __shared__ float lsum[16], lss[16];
  __shared__ float scs[10], shs[10];
  int tid = threadIdx.x, b = blockIdx.x;
  int f32 = ctrl[0];
  if (tid < 10){
    float m = psum[tid] * invN;
    float v = fmaxf(psq[tid] * invN - m*m, 0.f);
    float sc = ldin(g, tid, f32) * rsqrtf(v + 2e-5f);
    scs[tid] = sc;
    shs[tid] = ldin(bb, tid, f32) - m * sc;
  }
  for (int i = tid; i < 784; i += 512) xs2[i] = xa[(size_t)b*784 + i];
  for (int i = tid; i < 360; i += 512){
    int r = i / 90, rem = i % 90, o = rem / 9, t = rem % 9;
    wr1[i] = ldin(c1, o*9 + rot_src<3>(r, t), f32);
  }
  for (int i = tid; i < 2704; i += 512) attL[i] = attm[(size_t)b*2704 + i];
  if (tid < 16){ lsum[tid] = 0.f; lss[tid] = 0.f; }
  __syncthreads();
  for (int it = tid; it < 1040; it += 512){
    int row = it / 40, ch = it % 40;
    int ci = ch >> 2, s = ch & 3;
    float wt[9];
    {
      const float* wb = wr1 + (s*10 + ci)*9;
      #pragma unroll
      for (int t = 0; t < 9; ++t) wt[t] = wb[t];
    }
    float sc = scs[ci], sh = shs[ci];
    float acc[26];
    #pragma unroll
    for (int w = 0; w < 26; ++w) acc[w] = 0.f;
    #pragma unroll
    for (int u = 0; u < 3; ++u){
      float rr[28];
      const float4* rp = (const float4*)(xs2 + (row + u)*28);
      #pragma unroll
      for (int j = 0; j < 7; ++j){ float4 q = rp[j]; rr[4*j]=q.x; rr[4*j+1]=q.y; rr[4*j+2]=q.z; rr[4*j+3]=q.w; }
      #pragma unroll
      for (int v = 0; v < 3; ++v){
        float wv = wt[u*3 + v];
        #pragma unroll
        for (int w = 0; w < 26; ++w) acc[w] = fmaf(rr[w + v], wv, acc[w]);
      }
    }
    const float* ap = attL + s*676 + row*26;
    int gbase = (ch >> 3)*676 + row*26;
    int c7 = ch & 7;
    #pragma unroll
    for (int w = 0; w < 26; ++w){
      float v = fmaxf(fmaf(acc[w], sc, sh), 0.f) * ap[w];
      xin5[swz(gbase + w)*8 + c7] = bfbits(v);
    }
  }
  __syncthreads();

  int wv = tid >> 6, lane = tid & 63, lm = lane & 15, lq = lane >> 4;
  short8x bmain[9], btail[3];
  int tdh[3], tdw[3];
  #pragma unroll
  for (int tg = 0; tg < 3; ++tg){
    int tap = tg*4 + lq; if (tap > 8) tap = 8;
    tdh[tg] = tap / 3; tdw[tg] = tap % 3;
  }
  int curNt = -1, n = 0, o = 0;
  for (int u = wv; u < 54; u += 8){
    int nt = u / 18, mp = u % 18;
    if (nt != curNt){
      curNt = nt; n = nt*16 + lm; o = n >> 2;
      #pragma unroll
      for (int t = 0; t < 9; ++t)
        bmain[t] = *(const short8x*)(btg + (((t*4 + lq)*48 + n) << 3));
      #pragma unroll
      for (int tg = 0; tg < 3; ++tg)
        btail[tg] = *(const short8x*)(btg + 13824 + (((tg*4 + lq)*48 + n) << 3));
    }
    int mt0 = mp*2, mt1 = mp*2 + 1;
    int mA0 = mt0*16 + lm, mA1 = mt1*16 + lm;
    int qi0 = mA0 >> 2, sub0 = mA0 & 3;
    int h00 = 2*(qi0/12) + (sub0 >> 1), w00 = 2*(qi0%12) + (sub0 & 1);
    int qi1 = mA1 >> 2, sub1 = mA1 & 3;
    int h01 = 2*(qi1/12) + (sub1 >> 1), w01 = 2*(qi1%12) + (sub1 & 1);
    f32x4 acc0 = {0.f,0.f,0.f,0.f}, acc1 = {0.f,0.f,0.f,0.f};
    conv12x2<676,26>(xin5, h00*26 + w00, h01*26 + w01, lq, bmain, btail, tdh, tdw, acc0, acc1);
    if (n < 40){
      float s1 = acc0[0]+acc0[1]+acc0[2]+acc0[3] + acc1[0]+acc1[1]+acc1[2]+acc1[3];
      float s2 = acc0[0]*acc0[0]+acc0[1]*acc0[1]+acc0[2]*acc0[2]+acc0[3]*acc0[3]
               + acc1[0]*acc1[0]+acc1[1]*acc1[1]+acc1[2]*acc1[2]+acc1[3]*acc1[3];
      atomicAdd(&lsum[o], s1); atomicAdd(&lss[o], s2);
      float mx0 = fmaxf(fmaxf(acc0[0], acc0[1]), fmaxf(acc0[2], acc0[3]));
      float mx1 = fmaxf(fmaxf(acc1[0], acc1[1]), fmaxf(acc1[2], acc1[3]));
      size_t pbase = ((size_t)b*40 + n)*144;
      stv(ap2 + pbase + mt0*4 + lq, mx0);
      stv(ap2 + pbase + mt1*4 + lq, mx1);
    }
  }
  __syncthreads();
  if (tid < 10){ atomicAdd(&ssum[tid], lsum[tid]); atomicAdd(&ssq[tid], lss[tid]); }
}

// ---------------- generic GG conv via MFMA (L3/L4): coalesced staging + nt-outer B-in-regs ----------------
template<int HIN, int NT, typename TI>
__global__ __launch_bounds__(NT) void k_conv_ggm(const TI* __restrict__ act,
                                                 const float* __restrict__ psum,
                                                 const float* __restrict__ psq,
                                                 const void* __restrict__ g,
                                                 const void* __restrict__ bb,
                                                 float invN,
                                                 const float* __restrict__ attm,
                                                 const short* __restrict__ btg,
                                                 const int* __restrict__ ctrl,
                                                 float* __restrict__ out,
                                                 float* __restrict__ ssum, float* __restrict__ ssq){
  constexpr int WIN = HIN, HOUT = HIN - 2, WOUT = WIN - 2;
  constexpr int M = HOUT*WOUT, HW = HIN*WIN;
  constexpr int MT = (M + 15)/16, MU = (MT + 1)/2, UNITS = MU*3;
  constexpr int NWV = NT/64;
  constexpr int UP = ((5*HW + 7)/8)*8;
  __shared__ alignas(16) short xin5[UP*8];
  __shared__ float lsum[16], lss[16];
  __shared__ float scs[10], shs[10];
  int tid = threadIdx.x, b = blockIdx.x;
  int f32 = ctrl[0];
  if (tid < 10){
    float m = psum[tid]*invN;
    float v = fmaxf(psq[tid]*invN - m*m, 0.f);
    float sc = ldin(g, tid, f32)*rsqrtf(v + 2e-5f);
    scs[tid] = sc; shs[tid] = ldin(bb, tid, f32) - m*sc;
  }
  if (tid < 16){ lsum[tid] = 0.f; lss[tid] = 0.f; }
  __syncthreads();
  // coalesced: consecutive lanes -> consecutive sp within one channel
  for (int i = tid; i < HW*40; i += NT){
    int ch = i / HW, sp = i % HW;
    int ci = ch >> 2, s = ch & 3;
    float a = ldv(act + ((size_t)b*40 + ch)*HW + sp);
    a = fmaxf(fmaf(a, scs[ci], shs[ci]), 0.f);
    float v = a * attm[((size_t)b*4 + s)*HW + sp];
    xin5[swz((ch >> 3)*HW + sp)*8 + (ch & 7)] = bfbits(v);
  }
  __syncthreads();
  int wv = tid >> 6, lane = tid & 63, lm = lane & 15, lq = lane >> 4;
  short8x bmain[9], btail[3];
  int tdh[3], tdw[3];
  #pragma unroll
  for (int tg = 0; tg < 3; ++tg){
    int tap = tg*4 + lq; if (tap > 8) tap = 8;
    tdh[tg] = tap / 3; tdw[tg] = tap % 3;
  }
  int curNt = -1, n = 0, o = 0;
  for (int u = wv; u < UNITS; u += NWV){
    int nt = u / MU, mu = u % MU;
    if (nt != curNt){
      curNt = nt; n = nt*16 + lm; o = n >> 2;
      #pragma unroll
      for (int t = 0; t < 9; ++t)
        bmain[t] = *(const short8x*)(btg + (((t*4 + lq)*48 + n) << 3));
      #pragma unroll
      for (int tg = 0; tg < 3; ++tg)
        btail[tg] = *(const short8x*)(btg + 13824 + (((tg*4 + lq)*48 + n) << 3));
    }
    int mt0 = mu*2, mt1 = mu*2 + 1;
    int mA0 = mt0*16 + lm; if (mA0 > M-1) mA0 = M-1;
    int mA1 = mt1*16 + lm; if (mA1 > M-1) mA1 = M-1;
    int base0 = (mA0 / WOUT)*WIN + (mA0 % WOUT);
    int base1 = (mA1 / WOUT)*WIN + (mA1 % WOUT);
    f32x4 acc0 = {0.f,0.f,0.f,0.f}, acc1 = {0.f,0.f,0.f,0.f};
    conv12x2<HW,WIN>(xin5, base0, base1, lq, bmain, btail, tdh, tdw, acc0, acc1);
    if (n < 40){
      float s1 = 0.f, s2 = 0.f;
      size_t obase = ((size_t)b*40 + n)*M;
      #pragma unroll
      for (int reg = 0; reg < 4; ++reg){
        int m0 = mt0*16 + lq*4 + reg;
        if (m0 < M){ float v = acc0[reg]; s1 += v; s2 += v*v; out[obase + m0] = v; }
        int m1 = mt1*16 + lq*4 + reg;
        if (m1 < M){ float v = acc1[reg]; s1 += v; s2 += v*v; out[obase + m1] = v; }
      }
      atomicAdd(&lsum[o], s1); atomicAdd(&lss[o], s2);
    }
  }
  __syncthreads();
  if (tid < 10){ atomicAdd(&ssum[tid], lsum[tid]); atomicAdd(&ssq[tid], lss[tid]); }
}

// ---------------- generic GG spatial attention (L3..L7): 2 batch items per block ----------------
template<int H, int W, int NT, typename TA>
__global__ __launch_bounds__(NT) void k_att_gg(const TA* __restrict__ act,
                                               const float* __restrict__ psum,
                                               const float* __restrict__ psq,
                                               const void* __restrict__ g,
                                               const void* __restrict__ bb,
                                               float invN,
                                               const void* __restrict__ aw,
                                               const int* __restrict__ ctrl,
                                               float* __restrict__ att){
  constexpr int WG = (W + 6) | 1;
  constexpr int HW = H*W;
  constexpr int WH = W/2;
  constexpr int PSN = 8*H*WG;
  __shared__ float ps[2][PSN];
  __shared__ float wl[1568];
  __shared__ float scs[10], shs[10];
  int b0 = blockIdx.x*2, tid = threadIdx.x;
  int f32 = ctrl[0];
  if (tid < 10){
    float m = psum[tid]*invN;
    float v = fmaxf(psq[tid]*invN - m*m, 0.f);
    float sc = ldin(g, tid, f32)*rsqrtf(v + 2e-5f);
    scs[tid] = sc; shs[tid] = ldin(bb, tid, f32) - m*sc;
  }
  for (int i = tid; i < 1568; i += NT){
    int r = i / 392, rem = i % 392, i2 = rem / 196, s = (rem % 196)/49, t = rem % 49;
    int sp = (s - r) & 3;
    wl[i] = ldin(aw, (i2*4 + sp)*49 + rot_src<7>(r, t), f32);
  }
  __syncthreads();
  for (int i = tid; i < 2*4*H*WG; i += NT){
    int bi = i / (4*H*WG), rem0 = i % (4*H*WG);
    int b = b0 + bi;
    int s = rem0 / (H*WG), rem = rem0 % (H*WG), row = rem / WG, col = rem % WG;
    int cc = col - 3;
    float mn = 0.f, mx = 0.f;
    if (cc >= 0 && cc < W){
      float sum = 0.f; mx = 0.f;
      const TA* ap = act + (size_t)b*40*HW + (size_t)s*HW + row*W + cc;
      #pragma unroll
      for (int c = 0; c < 10; ++c){
        float v = fmaxf(fmaf(ldv(ap + (size_t)c*4*HW), scs[c], shs[c]), 0.f);
        sum += v; mx = fmaxf(mx, v);
      }
      mn = sum * 0.1f;
    }
    ps[bi][s*H*WG + row*WG + col] = mn;
    ps[bi][(4 + s)*H*WG + row*WG + col] = mx;
  }
  __syncthreads();
  for (int it = tid; it < 2*8*H; it += NT){
    int bi = it / (8*H), rem0 = it % (8*H);
    int b = b0 + bi;
    int r = rem0 / (2*H), rem2 = rem0 % (2*H), h = rem2 >> 1, half = rem2 & 1;
    int w0 = half*WH;
    float acc[WH];
    #pragma unroll
    for (int w = 0; w < WH; ++w) acc[w] = 0.f;
    for (int c = 0; c < 8; ++c){
      const float* wb = wl + r*392 + c*49;
      const float* pb = ps[bi] + c*H*WG;
      #pragma unroll
      for (int u = 0; u < 7; ++u){
        int row = h + u - 3;
        if (row < 0 || row >= H) continue;
        float rr[WH + 6];
        #pragma unroll
        for (int j = 0; j < WH + 6; ++j) rr[j] = pb[row*WG + w0 + j];
        #pragma unroll
        for (int v = 0; v < 7; ++v){
          float wv = wb[u*7 + v];
          #pragma unroll
          for (int w = 0; w < WH; ++w) acc[w] = fmaf(rr[w + v], wv, acc[w]);
        }
      }
    }
    size_t base = ((size_t)b*4 + r)*HW + (size_t)h*W + w0;
    #pragma unroll
    for (int w = 0; w < WH; ++w) att[base + w] = sigm(acc[w]);
  }
}

// ---------------- fp32 GG conv (L5..L7): 2 batch items per block ----------------
template<int HIN, int K, int SR, int NT, bool STATS, bool FINAL, typename TI>
__global__ __launch_bounds__(NT) void k_conv_gg(const TI* __restrict__ act,
                                                const float* __restrict__ psum,
                                                const float* __restrict__ psq,
                                                const void* __restrict__ g,
                                                const void* __restrict__ bb,
                                                float invN,
                                                const float* __restrict__ attm,
                                                const void* __restrict__ cw,
                                                const int* __restrict__ ctrl,
                                                void* __restrict__ out,
                                                float* __restrict__ ssum, float* __restrict__ ssq){
  constexpr int WIN  = HIN;
  constexpr int HOUT = HIN - K + 1;
  constexpr int WOUT = WIN - K + 1;
  constexpr int NS   = HOUT / SR;
  constexpr int WP   = WIN | 1;
  constexpr int NW   = 10*10*4*K*K;
  constexpr int HW   = HIN*WIN;
  constexpr int XN   = 40*HIN*WP;
  __shared__ float xin[2][XN];
  __shared__ float wl[NW];
  __shared__ float lsum[16], lss[16];
  __shared__ float scs[10], shs[10];
  __shared__ float red[2][48];
  int tid = threadIdx.x;
  int b0 = blockIdx.x*2;
  int f32 = ctrl[0];
  if (tid < 10){
    float m = psum[tid]*invN;
    float v = fmaxf(psq[tid]*invN - m*m, 0.f);
    float sc = ldin(g, tid, f32)*rsqrtf(v + 2e-5f);
    scs[tid] = sc; shs[tid] = ldin(bb, tid, f32) - m*sc;
  }
  if (STATS && tid < 16){ lsum[tid] = 0.f; lss[tid] = 0.f; }
  for (int i = tid; i < NW; i += NT) wl[i] = ldin(cw, i, f32);
  __syncthreads();
  for (int i = tid; i < 2*XN; i += NT){
    int bi = i / XN, rem0 = i % XN;
    int b = b0 + bi;
    int c = rem0 / (HIN*WP), rem = rem0 % (HIN*WP), rr = rem / WP, col = rem % WP;
    float v = 0.f;
    if (col < WIN){
      int ch = c >> 2, s = c & 3;
      float a = ldv(act + ((size_t)b*40 + c)*HW + (size_t)rr*WIN + col);
      a = fmaxf(fmaf(a, scs[ch], shs[ch]), 0.f);
      v = a * attm[((size_t)b*4 + s)*HW + (size_t)rr*WIN + col];
    }
    xin[bi][rem0] = v;
  }
  __syncthreads();
  for (int it = tid; it < 2*40*NS; it += NT){
    int bi = it / (40*NS), rem0 = it % (40*NS);
    int b = b0 + bi;
    int o = rem0 / (4*NS), rem = rem0 % (4*NS), r = rem / NS, hs = rem % NS;
    int h0 = hs * SR;
    int perm[K*K];
    #pragma unroll
    for (int t = 0; t < K*K; ++t) perm[t] = rot_src<K>(r, t);
    float acc[SR][WOUT];
    #pragma unroll
    for (int a = 0; a < SR; ++a)
      #pragma unroll
      for (int w = 0; w < WOUT; ++w) acc[a][w] = 0.f;
    for (int ci = 0; ci < 10; ++ci){
      #pragma unroll
      for (int s = 0; s < 4; ++s){
        int sp = (s - r) & 3;
        const float* wb = wl + (size_t)((o*10 + ci)*4 + sp)*K*K;
        float wt[K*K];
        #pragma unroll
        for (int t = 0; t < K*K; ++t) wt[t] = wb[perm[t]];
        const float* ib = xin[bi] + (ci*4 + s)*HIN*WP;
        #pragma unroll
        for (int ri = 0; ri < SR + K - 1; ++ri){
          float rr3[WP];
          #pragma unroll
          for (int j = 0; j < WP; ++j) rr3[j] = ib[(h0 + ri)*WP + j];
          #pragma unroll
          for (int u = 0; u < K; ++u){
            int orr = ri - u;
            if (orr < 0 || orr >= SR) continue;
            #pragma unroll
            for (int v = 0; v < K; ++v){
              float wv = wt[u*K + v];
              #pragma unroll
              for (int w = 0; w < WOUT; ++w) acc[orr][w] = fmaf(rr3[w + v], wv, acc[orr][w]);
            }
          }
        }
      }
    }
    if constexpr (STATS){
      float s1 = 0.f, s2 = 0.f;
      #pragma unroll
      for (int a = 0; a < SR; ++a)
        #pragma unroll
        for (int w = 0; w < WOUT; ++w){ s1 += acc[a][w]; s2 += acc[a][w]*acc[a][w]; }
      atomicAdd(&lsum[o], s1); atomicAdd(&lss[o], s2);
    }
    if constexpr (FINAL){
      red[bi][o*4 + r] = acc[0][0];
    } else {
      #pragma unroll
      for (int a = 0; a < SR; ++a){
        size_t base = ((size_t)b*40 + o*4 + r)*HOUT*WOUT + (size_t)(h0 + a)*WOUT;
        #pragma unroll
        for (int w = 0; w < WOUT; ++w) ((float*)out)[base + w] = acc[a][w];
      }
    }
  }
  if constexpr (STATS){
    __syncthreads();
    if (tid < 10){ atomicAdd(&ssum[tid], lsum[tid]); atomicAdd(&ssq[tid], lss[tid]); }
  }
  if constexpr (FINAL){
    __syncthreads();
    if (tid < 20){
      int bi = tid / 10, c = tid % 10;
      float m4 = fmaxf(fmaxf(red[bi][c*4], red[bi][c*4+1]), fmaxf(red[bi][c*4+2], red[bi][c*4+3]));
      if (f32) ((float*)out)[(size_t)(b0 + bi)*10 + c] = m4;
      else stv((bf*)out + (size_t)(b0 + bi)*10 + c, m4);
    }
  }
}

extern "C" void kernel_launch(void* const* d_in, const int* in_sizes, int n_in,
                              void* d_out, int out_size, void* d_ws, size_t ws_size,
                              hipStream_t stream){
  (void)in_sizes; (void)n_in; (void)out_size; (void)ws_size;
  const void* x  = d_in[0];
  const void* c1 = d_in[1];
  const void* a1 = d_in[2];
  const void* c2 = d_in[3];
  const void* a2 = d_in[4];
  const void* c3 = d_in[5];
  const void* a3 = d_in[6];
  const void* c4 = d_in[7];
  const void* a4 = d_in[8];
  const void* c5 = d_in[9];
  const void* a5 = d_in[10];
  const void* c6 = d_in[11];
  const void* a6 = d_in[12];
  const void* c7 = d_in[13];
  const void* a7 = d_in[14];
  const void* bng[6] = {d_in[15],d_in[17],d_in[19],d_in[21],d_in[23],d_in[25]};
  const void* bnb[6] = {d_in[16],d_in[18],d_in[20],d_in[22],d_in[24],d_in[26]};

  // ---- arena ----
  size_t off = 0;
  char* wsb = (char*)d_ws;
  auto alloc = [&](size_t bytes)->void*{ void* p = wsb + off; off += (bytes + 255) & ~(size_t)255; return p; };
  int*   ctrl   = (int*)alloc(256);
  float* stats  = (float*)alloc(192*sizeof(float));
  float* scales = (float*)alloc(192*sizeof(float));
  (void)scales;
  short* btfr   = (short*)alloc(3*18432*2);
  char*  region1 = (char*)alloc(28573696);
  bf*    ap2 = (bf*)alloc((size_t)2048*40*144*2);
  float* yD  = (float*)alloc((size_t)2048*40*100*4);
  float* xa    = (float*)region1;
  float* attf2 = (float*)(region1 + 6422528);
  float* yE    = (float*)region1;
  float* attf3 = (float*)(region1 + 20971520);

  hipMemsetAsync(ctrl, 0, 1024, stream);
  k_detect<<<1, 64, 0, stream>>>(x, ctrl);
  k_build_bt<<<3, 256, 0, stream>>>(c2, c3, c4, ctrl, btfr);

  // L1 (2 items/block)
  k_l1<<<2048, 512, 0, stream>>>(x, a1, c1, ctrl, xa, stats + 0, stats + 16);

  // L2 (bn1 finalize fused in consumers)
  k_att2<<<2048, 256, 0, stream>>>(xa, c1, stats + 0, stats + 16, bng[0], bnb[0],
                                   1.f/5537792.f, a2, ctrl, attf2);
  k_conv2m<<<2048, 512, 0, stream>>>(xa, c1, stats + 0, stats + 16, bng[0], bnb[0],
                                     1.f/5537792.f, attf2, btfr, ctrl, ap2, stats + 32, stats + 48);

  // L3: 12->10 (MFMA)
  k_att_gg<12,12,256,bf><<<1024, 256, 0, stream>>>(ap2, stats + 32, stats + 48, bng[1], bnb[1],
                                                   1.f/4718592.f, a3, ctrl, attf3);
  k_conv_ggm<12,256,bf><<<2048, 256, 0, stream>>>(ap2, stats + 32, stats + 48, bng[1], bnb[1],
                                                  1.f/4718592.f, attf3, btfr + 18432, ctrl,
                                                  yD, stats + 64, stats + 80);

  // L4: 10->8 (MFMA)
  k_att_gg<10,10,256,float><<<1024, 256, 0, stream>>>(yD, stats + 64, stats + 80, bng[2], bnb[2],
                                                      1.f/819200.f, a4, ctrl, attf3);
  k_conv_ggm<10,256,float><<<2048, 256, 0, stream>>>(yD, stats + 64, stats + 80, bng[2], bnb[2],
                                                     1.f/819200.f, attf3, btfr + 36864, ctrl,
                                                     yE, stats + 96, stats + 112);

  // L5: 8->6 (fp32, SR=1, batched x2, 512 thr)
  k_att_gg<8,8,256,float><<<1024, 256, 0, stream>>>(yE, stats + 96, stats + 112, bng[3], bnb[3],
                                                    1.f/524288.f, a5, ctrl, attf3);
  k_conv_gg<8,3,1,512,true,false,float><<<1024, 512, 0, stream>>>(yE, stats + 96, stats + 112,
                                                  bng[3], bnb[3], 1.f/524288.f, attf3, c5, ctrl,
                                                  yD, stats + 128, stats + 144);

  // L6: 6->4 (fp32, SR=1, batched x2, 384 thr)
  k_att_gg<6,6,256,float><<<1024, 256, 0, stream>>>(yD, stats + 128, stats + 144, bng[4], bnb[4],
                                                    1.f/294912.f, a6, ctrl, attf3);
  k_conv_gg<6,3,1,384,true,false,float><<<1024, 384, 0, stream>>>(yD, stats + 128, stats + 144,
                                                  bng[4], bnb[4], 1.f/294912.f, attf3, c6, ctrl,
                                                  yE, stats + 160, stats + 176);

  // L7: 4x4 -> 1x1 + orientation group-max -> d_out (batched x2, 128 thr)
  k_att_gg<4,4,256,float><<<1024, 256, 0, stream>>>(yE, stats + 160, stats + 176, bng[5], bnb[5],
                                                    1.f/131072.f, a7, ctrl, attf3);
  k_conv_gg<4,4,1,128,false,true,float><<<1024, 128, 0, stream>>>(yE, stats + 160, stats + 176,
                                                  bng[5], bnb[5], 1.f/131072.f, attf3, c7, ctrl,
                                                  d_out, (float*)nullptr, (float*)nullptr);
}